// Round 15
// baseline (163.284 us; speedup 1.0000x reference)
//
#include <hip/hip_runtime.h>
#include <hip/hip_bf16.h>
#include <cstdint>

// Problem constants
#define DIMC  256
#define NH    8
#define HD    32
#define NPIX  2304       // 48*48
#define BATCH 2
#define NSPLIT 6
#define KPS   384        // keys per split (2304/6)
#define KT    32
#define NT    (KPS / KT) // 12

typedef short s16x8 __attribute__((ext_vector_type(8)));
typedef short s16x4 __attribute__((ext_vector_type(4)));
typedef float f32x4 __attribute__((ext_vector_type(4)));

#define MFMA32(A,B,C) __builtin_amdgcn_mfma_f32_16x16x32_bf16(A,B,C,0,0,0)

// RNA (round-to-nearest-away) bf16 helpers: 1 VALU each.
__device__ inline uint32_t rnau(float x) { return __float_as_uint(x) + 0x8000u; }
__device__ inline uint32_t pk2(uint32_t l_, uint32_t h_) {
  return __builtin_amdgcn_perm(h_, l_, 0x07060302u);
}
__device__ inline float hif(uint32_t a) { return __uint_as_float(a & 0xffff0000u); }

// ---------------------------------------------------------------------------
// Pool: x_avg = (x + box3/9 + box5/25 + box7/49)/4, zero-pad, include_pad
// ---------------------------------------------------------------------------
__global__ __launch_bounds__(256) void pool_kernel(const float* __restrict__ x,
                                                   float* __restrict__ xavg) {
  const int plane = blockIdx.x;
  const float* xp = x + (size_t)plane * NPIX;
  __shared__ float sx[NPIX];
  __shared__ float h3[NPIX], h5[NPIX], h7[NPIX];
  const int t = threadIdx.x;
#pragma unroll
  for (int r = 0; r < 9; ++r) sx[r * 256 + t] = xp[r * 256 + t];
  __syncthreads();
#pragma unroll
  for (int r = 0; r < 9; ++r) {
    int p = r * 256 + t;
    int i = p / 48, j = p - i * 48;
    float a3 = 0.f, a5 = 0.f, a7 = 0.f;
#pragma unroll
    for (int dj = -3; dj <= 3; ++dj) {
      int jj = j + dj;
      if (jj < 0 || jj >= 48) continue;
      float v = sx[i * 48 + jj];
      a7 += v;
      if (dj >= -2 && dj <= 2) a5 += v;
      if (dj >= -1 && dj <= 1) a3 += v;
    }
    h3[p] = a3; h5[p] = a5; h7[p] = a7;
  }
  __syncthreads();
#pragma unroll
  for (int r = 0; r < 9; ++r) {
    int p = r * 256 + t;
    int i = p / 48, j = p - i * 48;
    float b3 = 0.f, b5 = 0.f, b7 = 0.f;
#pragma unroll
    for (int di = -3; di <= 3; ++di) {
      int ii = i + di;
      if (ii < 0 || ii >= 48) continue;
      int q = ii * 48 + j;
      b7 += h7[q];
      if (di >= -2 && di <= 2) b5 += h5[q];
      if (di >= -1 && di <= 1) b3 += h3[q];
    }
    xavg[(size_t)plane * NPIX + p] =
        0.25f * (sx[p] + b3 * (1.f / 9.f) + b5 * (1.f / 25.f) + b7 * (1.f / 49.f));
  }
}

// ---------------------------------------------------------------------------
// Fused converts: blocks 0..287 tconv(x), 288..575 tconv(xavg), 576..703 wconv
// tconv: HI-ONLY. wconv keeps hi+lo (proj gemm uses both). UNCHANGED from R14.
// ---------------------------------------------------------------------------
__global__ __launch_bounds__(256) void conv_all(
    const float* __restrict__ x, const float* __restrict__ xavg,
    const float* __restrict__ qw, const float* __restrict__ kvw,
    const float* __restrict__ pw_,
    short* __restrict__ Xh, short* __restrict__ Ah,
    short* __restrict__ Wth, short* __restrict__ Wtl) {
  const int bx = blockIdx.x;
  const int t = threadIdx.x;
  if (bx < 576) {
    const float* src = (bx < 288) ? x : xavg;
    short* dhi = (bx < 288) ? Xh : Ah;
    const int bb = (bx < 288) ? bx : bx - 288;
    const int n0 = (bb % 36) * 64, c0 = ((bb / 36) & 3) * 64, b = bb / 144;
    __shared__ __align__(16) float T[64][68];
    {
      const int c = t >> 2, n4 = (t & 3) * 16;
      const float* sp = src + ((size_t)b * DIMC + c0 + c) * NPIX + n0 + n4;
#pragma unroll
      for (int i2 = 0; i2 < 4; ++i2)
        *(f32x4*)&T[c][n4 + i2 * 4] = *(const f32x4*)(sp + i2 * 4);
    }
    __syncthreads();
    {
      const int n = t >> 2, c4 = (t & 3) * 16;
      float v[16];
#pragma unroll
      for (int i = 0; i < 16; ++i) v[i] = T[c4 + i][n];
      uint32_t a[16];
#pragma unroll
      for (int i = 0; i < 16; ++i) a[i] = rnau(v[i]);
      union { s16x8 s; uint32_t u[4]; } H0, H1;
#pragma unroll
      for (int j = 0; j < 4; ++j) {
        H0.u[j] = pk2(a[2 * j], a[2 * j + 1]);
        H1.u[j] = pk2(a[8 + 2 * j], a[8 + 2 * j + 1]);
      }
      const size_t off = ((size_t)b * NPIX + n0 + n) * DIMC + c0 + c4;
      *(s16x8*)(dhi + off) = H0.s; *(s16x8*)(dhi + off + 8) = H1.s;
    }
  } else {
    const int idx = ((bx - 576) * 256 + t) * 8;
    const float* s;
    int off;
    if (idx < 65536)       { s = qw;  off = idx; }
    else if (idx < 196608) { s = kvw; off = idx - 65536; }
    else                   { s = pw_; off = idx - 196608; }
    f32x4 x0 = *(const f32x4*)(s + off);
    f32x4 x1 = *(const f32x4*)(s + off + 4);
    float v[8] = {x0[0], x0[1], x0[2], x0[3], x1[0], x1[1], x1[2], x1[3]};
    uint32_t a[8], al[8];
#pragma unroll
    for (int i = 0; i < 8; ++i) a[i] = rnau(v[i]);
#pragma unroll
    for (int i = 0; i < 8; ++i) al[i] = rnau(v[i] - hif(a[i]));
    union { s16x8 s; uint32_t u[4]; } H, L;
#pragma unroll
    for (int j = 0; j < 4; ++j) {
      H.u[j] = pk2(a[2 * j], a[2 * j + 1]);
      L.u[j] = pk2(al[2 * j], al[2 * j + 1]);
    }
    *(s16x8*)(Wth + idx) = H.s;
    *(s16x8*)(Wtl + idx) = L.s;
  }
}

// ---------------------------------------------------------------------------
// GEMM body (proj only): 3 MFMAs hi/lo. UNCHANGED.
// ---------------------------------------------------------------------------
__device__ __forceinline__ void gemm_body(
    const short* __restrict__ Wh, const short* __restrict__ Wl,
    const float* __restrict__ bias,
    const short* __restrict__ Inh, const short* __restrict__ Inl,
    float* __restrict__ outf,
    int n0, int o0, int b, float (*Cl)[68]) {
  const int tid = threadIdx.x;
  const int wave = tid >> 6, lane = tid & 63;
  const int g = lane >> 4, q = lane & 15;

  const short* wph = Wh + ((o0 + wave * 16 + q) * DIMC + g * 8);
  const short* wpl = Wl + ((o0 + wave * 16 + q) * DIMC + g * 8);
  const short* iph = Inh + ((size_t)(b * NPIX + n0 + q) * DIMC + g * 8);
  const short* ipl = Inl + ((size_t)(b * NPIX + n0 + q) * DIMC + g * 8);

  f32x4 acc[4] = {{0,0,0,0},{0,0,0,0},{0,0,0,0},{0,0,0,0}};
#pragma unroll
  for (int c0 = 0; c0 < DIMC; c0 += 32) {
    s16x8 ah = *(const s16x8*)(wph + c0);
    s16x8 al = *(const s16x8*)(wpl + c0);
#pragma unroll
    for (int st = 0; st < 4; ++st) {
      s16x8 bh_ = *(const s16x8*)(iph + (size_t)st * 16 * DIMC + c0);
      s16x8 bl_ = *(const s16x8*)(ipl + (size_t)st * 16 * DIMC + c0);
      acc[st] = MFMA32(ah, bh_, acc[st]);
      acc[st] = MFMA32(ah, bl_, acc[st]);
      acc[st] = MFMA32(al, bh_, acc[st]);
    }
  }
#pragma unroll
  for (int st = 0; st < 4; ++st)
#pragma unroll
    for (int r = 0; r < 4; ++r)
      Cl[wave * 16 + g * 4 + r][st * 16 + q] = acc[st][r];
  __syncthreads();

  const int o = tid >> 2, nc = (tid & 3) * 16;
  const float bv = bias[o0 + o];
  float* op = outf + ((size_t)b * DIMC + o0 + o) * NPIX + n0 + nc;
#pragma unroll
  for (int i2 = 0; i2 < 4; ++i2) {
    f32x4 v = *(const f32x4*)&Cl[o][nc + i2 * 4];
    v[0] += bv; v[1] += bv; v[2] += bv; v[3] += bv;
    *(f32x4*)(op + i2 * 4) = v;
  }
}

__global__ __launch_bounds__(128) void gemm_proj(
    const short* __restrict__ Wh, const short* __restrict__ Wl,
    const float* __restrict__ bias,
    const short* __restrict__ Zh, const short* __restrict__ Zl,
    float* __restrict__ out) {
  __shared__ __align__(16) float Cl[32][68];
  gemm_body(Wh, Wl, bias, Zh, Zl, out,
            blockIdx.x * 64, blockIdx.y * 32, blockIdx.z, Cl);
}

// ---------------------------------------------------------------------------
// QKV GEMM, fully specialized hi-only inputs, 2 MFMAs. UNCHANGED from R13.
// ---------------------------------------------------------------------------
__global__ __launch_bounds__(128) void gemm_qkv_hi(
    const short* __restrict__ Wth, const short* __restrict__ Wtl,
    const float* __restrict__ q_b, const float* __restrict__ kv_b,
    const short* __restrict__ Xh, const short* __restrict__ Ah,
    short* __restrict__ Qhi, short* __restrict__ Khi, short* __restrict__ Vhi,
    float qscale) {
  __shared__ __align__(16) float Cl[32][68];
  const int by = blockIdx.y;
  const bool isQ = (by < 8);
  const int o0 = isQ ? by * 32 : (by - 8) * 32;
  const short* Wh = isQ ? Wth : Wth + 65536;
  const short* Wl = isQ ? Wtl : Wtl + 65536;
  const float* bias = isQ ? q_b : kv_b;
  const short* Inh = isQ ? Xh : Ah;
  const float scale = isQ ? qscale : 1.0f;
  short* d1 = isQ ? Qhi : Khi;   // used when o0 < 256 (Q or K)
  const int n0 = blockIdx.x * 64;
  const int b  = blockIdx.z;

  const int tid = threadIdx.x;
  const int wave = tid >> 6, lane = tid & 63;
  const int g = lane >> 4, q = lane & 15;

  const short* wph = Wh + ((o0 + wave * 16 + q) * DIMC + g * 8);
  const short* wpl = Wl + ((o0 + wave * 16 + q) * DIMC + g * 8);
  const short* iph = Inh + ((size_t)(b * NPIX + n0 + q) * DIMC + g * 8);

  f32x4 acc[4] = {{0,0,0,0},{0,0,0,0},{0,0,0,0},{0,0,0,0}};
#pragma unroll
  for (int c0 = 0; c0 < DIMC; c0 += 32) {
    s16x8 ah = *(const s16x8*)(wph + c0);
    s16x8 al = *(const s16x8*)(wpl + c0);
#pragma unroll
    for (int st = 0; st < 4; ++st) {
      s16x8 bh_ = *(const s16x8*)(iph + (size_t)st * 16 * DIMC + c0);
      acc[st] = MFMA32(ah, bh_, acc[st]);
      acc[st] = MFMA32(al, bh_, acc[st]);
    }
  }
#pragma unroll
  for (int st = 0; st < 4; ++st)
#pragma unroll
    for (int r = 0; r < 4; ++r)
      Cl[wave * 16 + g * 4 + r][st * 16 + q] = acc[st][r];
  __syncthreads();

  if (o0 < 256) {
    // Q or K: (C+bias)*scale, hi-only, layout [bh][n][32]
    const int n = tid >> 1, oq = tid & 1;
    const int h = o0 >> 5;
    const float* bp = bias + o0 + oq * 16;
    float v[16];
#pragma unroll
    for (int i = 0; i < 16; ++i) v[i] = (Cl[oq * 16 + i][n] + bp[i]) * scale;
    uint32_t a[16];
#pragma unroll
    for (int i = 0; i < 16; ++i) a[i] = rnau(v[i]);
    union { s16x8 s; uint32_t u[4]; } H0, H1;
#pragma unroll
    for (int j = 0; j < 4; ++j) {
      H0.u[j] = pk2(a[2 * j], a[2 * j + 1]);
      H1.u[j] = pk2(a[8 + 2 * j], a[8 + 2 * j + 1]);
    }
    const size_t off = ((size_t)((b * 8 + h) * NPIX + n0 + n)) * HD + oq * 16;
    *(s16x8*)(d1 + off) = H0.s; *(s16x8*)(d1 + off + 8) = H1.s;
  } else {
    // V hi-only: dst [bh][d][n]
    const int o = tid >> 2, nc = (tid & 3) * 16;
    const int h = (o0 - 256) >> 5;
    const float bv = bias[o0 + o];
    float v[16];
#pragma unroll
    for (int i2 = 0; i2 < 4; ++i2) {
      f32x4 t4 = *(const f32x4*)&Cl[o][nc + i2 * 4];
      v[i2 * 4 + 0] = t4[0] + bv; v[i2 * 4 + 1] = t4[1] + bv;
      v[i2 * 4 + 2] = t4[2] + bv; v[i2 * 4 + 3] = t4[3] + bv;
    }
    uint32_t a[16];
#pragma unroll
    for (int i = 0; i < 16; ++i) a[i] = rnau(v[i]);
    union { s16x8 s; uint32_t u[4]; } H0, H1;
#pragma unroll
    for (int j = 0; j < 4; ++j) {
      H0.u[j] = pk2(a[2 * j], a[2 * j + 1]);
      H1.u[j] = pk2(a[8 + 2 * j], a[8 + 2 * j + 1]);
    }
    const size_t off = ((size_t)((b * 8 + h) * HD + o)) * NPIX + n0 + nc;
    *(s16x8*)(Vhi + off) = H0.s; *(s16x8*)(Vhi + off + 8) = H1.s;
  }
}

// ---------------------------------------------------------------------------
// MFMA flash attention — R13 structure + two changes:
//  (a) 3-slot ring prefetch (loads issued 2 tiles ahead: ~300cyc latency cover)
//  (b) l-sum via MFMA with A=ones (replaces 16 VALU adds/iter + final shuffles;
//      l now sums the ROUNDED P, consistent with what PV applies)
// ---------------------------------------------------------------------------
__global__ __launch_bounds__(128) void attn_mfma(
    const short* __restrict__ Qhi,   // [bh][n][32]
    const short* __restrict__ Khi,   // [bh][n][32]
    const short* __restrict__ Vhi,   // [bh][32][N]
    float* __restrict__ part_o,      // [row][NSPLIT][32]
    float* __restrict__ part_l) {    // [row][NSPLIT]
  const int sb = blockIdx.x;        // 0..575 = 16 bh * 36 qb
  const int bh = sb / 36;
  const int qb = sb % 36;           // 64-row block
  const int split = blockIdx.y;     // 0..NSPLIT-1
  const int tid = threadIdx.x;
  const int wave = tid >> 6, lane = tid & 63;
  const int g = lane >> 4, q = lane & 15;
  const int base = qb * 64 + wave * 32;

  __shared__ __align__(16) short Plds[2][2][16 * 40];
  short* pwA = &Plds[wave][0][0];
  short* pwB = &Plds[wave][1][0];

  const size_t qoff = ((size_t)bh * NPIX + base + q) * HD + g * 8;
  const s16x8 qhA = *(const s16x8*)(Qhi + qoff);
  const s16x8 qhB = *(const s16x8*)(Qhi + qoff + 16 * HD);

  const short* kp = Khi + ((size_t)bh * NPIX + split * KPS + q) * HD + g * 8;
  const short* vp = Vhi + ((size_t)bh * HD + q) * NPIX + split * KPS + g * 8;

  const f32x4 Z4 = {0.f, 0.f, 0.f, 0.f};
  f32x4 OA0 = Z4, OA1 = Z4, OB0 = Z4, OB1 = Z4;
  f32x4 LA = Z4, LB = Z4;     // l accumulators (MFMA, all rows identical)
  s16x8 kb[3][2], vb[3][2], pfA, pfB, vp0, vp1;

  // A=ones fragment (bf16 1.0 = 0x3F80)
  union { s16x8 s; uint32_t u[4]; } ONE;
  ONE.u[0] = 0x3F803F80u; ONE.u[1] = 0x3F803F80u;
  ONE.u[2] = 0x3F803F80u; ONE.u[3] = 0x3F803F80u;
  const s16x8 ones = ONE.s;

  // prologue: tiles 0 and 1
  kb[0][0] = *(const s16x8*)(kp);
  kb[0][1] = *(const s16x8*)(kp + 16 * HD);
  vb[0][0] = *(const s16x8*)(vp);
  vb[0][1] = *(const s16x8*)(vp + 16 * NPIX);
  kb[1][0] = *(const s16x8*)(kp + KT * HD);
  kb[1][1] = *(const s16x8*)(kp + KT * HD + 16 * HD);
  vb[1][0] = *(const s16x8*)(vp + KT);
  vb[1][1] = *(const s16x8*)(vp + KT + 16 * NPIX);

#pragma unroll
  for (int t = 0; t < NT; ++t) {
    const int cur = t % 3;
    if (t + 2 < NT) {                // prefetch tile t+2 (2-iter latency cover)
      const int nx2 = (t + 2) % 3;
      const short* kpn = kp + (t + 2) * (KT * HD);
      const short* vpn = vp + (t + 2) * KT;
      kb[nx2][0] = *(const s16x8*)(kpn);
      kb[nx2][1] = *(const s16x8*)(kpn + 16 * HD);
      vb[nx2][0] = *(const s16x8*)(vpn);
      vb[nx2][1] = *(const s16x8*)(vpn + 16 * NPIX);
    }
    f32x4 SA0 = MFMA32(kb[cur][0], qhA, Z4);
    f32x4 SA1 = MFMA32(kb[cur][1], qhA, Z4);
    f32x4 SB0 = MFMA32(kb[cur][0], qhB, Z4);
    f32x4 SB1 = MFMA32(kb[cur][1], qhB, Z4);
    if (t > 0) {   // PV + l for tile t-1 (pf read issued last iter)
      OA0 = MFMA32(vp0, pfA, OA0);
      OA1 = MFMA32(vp1, pfA, OA1);
      OB0 = MFMA32(vp0, pfB, OB0);
      OB1 = MFMA32(vp1, pfB, OB1);
      LA  = MFMA32(ones, pfA, LA);
      LB  = MFMA32(ones, pfB, LB);
    }
    {   // q-tile A softmax weights
      f32x4 p0, p1;
#pragma unroll
      for (int r = 0; r < 4; ++r) { p0[r] = exp2f(SA0[r]); p1[r] = exp2f(SA1[r]); }
      uint2 w0, w1;
      w0.x = pk2(rnau(p0[0]), rnau(p0[1])); w0.y = pk2(rnau(p0[2]), rnau(p0[3]));
      w1.x = pk2(rnau(p1[0]), rnau(p1[1])); w1.y = pk2(rnau(p1[2]), rnau(p1[3]));
      *(uint2*)&pwA[q * 40 + g * 4] = w0;
      *(uint2*)&pwA[q * 40 + 16 + g * 4] = w1;
    }
    {   // q-tile B
      f32x4 p0, p1;
#pragma unroll
      for (int r = 0; r < 4; ++r) { p0[r] = exp2f(SB0[r]); p1[r] = exp2f(SB1[r]); }
      uint2 w0, w1;
      w0.x = pk2(rnau(p0[0]), rnau(p0[1])); w0.y = pk2(rnau(p0[2]), rnau(p0[3]));
      w1.x = pk2(rnau(p1[0]), rnau(p1[1])); w1.y = pk2(rnau(p1[2]), rnau(p1[3]));
      *(uint2*)&pwB[q * 40 + g * 4] = w0;
      *(uint2*)&pwB[q * 40 + 16 + g * 4] = w1;
    }
    vp0 = vb[cur][0]; vp1 = vb[cur][1];
    pfA = *(const s16x8*)&pwA[q * 40 + g * 8];   // consumed next iter
    pfB = *(const s16x8*)&pwB[q * 40 + g * 8];
  }
  // epilogue: PV + l for last tile
  OA0 = MFMA32(vp0, pfA, OA0);
  OA1 = MFMA32(vp1, pfA, OA1);
  OB0 = MFMA32(vp0, pfB, OB0);
  OB1 = MFMA32(vp1, pfB, OB1);
  LA  = MFMA32(ones, pfA, LA);
  LB  = MFMA32(ones, pfB, LB);

  const int rowA = bh * NPIX + base + q;
  const int rowB = rowA + 16;
  float* poA = part_o + ((size_t)rowA * NSPLIT + split) * HD;
  float* poB = part_o + ((size_t)rowB * NSPLIT + split) * HD;
  *(f32x4*)(poA + g * 4) = OA0;
  *(f32x4*)(poA + 16 + g * 4) = OA1;
  *(f32x4*)(poB + g * 4) = OB0;
  *(f32x4*)(poB + 16 + g * 4) = OB1;
  if (g == 0) {
    // LA[r] identical for all r and all g (A=ones): LA[0] = l for column q
    part_l[(size_t)rowA * NSPLIT + split] = LA[0];
    part_l[(size_t)rowB * NSPLIT + split] = LB[0];
  }
}

// ---------------------------------------------------------------------------
// Merge splits, emit SCRAMBLED z hi/lo [b][p][256]. 256 blocks. UNCHANGED.
// ---------------------------------------------------------------------------
__global__ __launch_bounds__(288) void attn_merge(const float* __restrict__ part_o,
                                                  const float* __restrict__ part_l,
                                                  short* __restrict__ zh,
                                                  short* __restrict__ zl) {
  const int blk = blockIdx.x;          // 256 = 16 bh * 16
  const int bh = blk >> 4;
  const int n0 = (blk & 15) * 144;
  const int head = bh & 7, b = bh >> 3;
  const int t = threadIdx.x;
  __shared__ __align__(16) float T[144][36];
  {
    const int r = t >> 1, uh = (t & 1) * 4;   // r in 0..143
    const int idx = bh * NPIX + n0 + r;
    const float* pl = part_l + (size_t)idx * NSPLIT;
    float L = 0.f;
#pragma unroll
    for (int s = 0; s < NSPLIT; ++s) L += pl[s];
    const float inv = 1.f / L;
    const float* po = part_o + (size_t)idx * (NSPLIT * HD);
#pragma unroll
    for (int u = 0; u < 4; ++u) {
      f32x4 v = {0.f, 0.f, 0.f, 0.f};
#pragma unroll
      for (int s = 0; s < NSPLIT; ++s)
        v += *(const f32x4*)(po + s * HD + (uh + u) * 4);
      v[0] *= inv; v[1] *= inv; v[2] *= inv; v[3] *= inv;
      *(f32x4*)&T[r][(uh + u) * 4] = v;
    }
  }
  __syncthreads();
  {
    const int r9 = t / 32, dd = t & 31;    // r9 in 0..8
    const int p = r9 * 256 + head * HD + dd;
    const int c0 = n0 / 9;                  // 16 channels per chunk
    float v[16];
#pragma unroll
    for (int j = 0; j < 16; ++j) v[j] = T[9 * j + r9][dd];
    uint32_t a[16], al[16];
#pragma unroll
    for (int j = 0; j < 16; ++j) a[j] = rnau(v[j]);
#pragma unroll
    for (int j = 0; j < 16; ++j) al[j] = rnau(v[j] - hif(a[j]));
    const size_t off = ((size_t)b * NPIX + p) * DIMC + c0;
#pragma unroll
    for (int c8 = 0; c8 < 2; ++c8) {
      union { s16x8 s; uint32_t u[4]; } H, L;
#pragma unroll
      for (int j = 0; j < 4; ++j) {
        H.u[j] = pk2(a[c8 * 8 + 2 * j], a[c8 * 8 + 2 * j + 1]);
        L.u[j] = pk2(al[c8 * 8 + 2 * j], al[c8 * 8 + 2 * j + 1]);
      }
      *(s16x8*)(zh + off + c8 * 8) = H.s;
      *(s16x8*)(zl + off + c8 * 8) = L.s;
    }
  }
}

// ---------------------------------------------------------------------------
extern "C" void kernel_launch(void* const* d_in, const int* in_sizes, int n_in,
                              void* d_out, int out_size, void* d_ws, size_t ws_size,
                              hipStream_t stream) {
  const float* x      = (const float*)d_in[0];
  const float* q_w    = (const float*)d_in[1];
  const float* q_b    = (const float*)d_in[2];
  const float* kv_w   = (const float*)d_in[3];
  const float* kv_b   = (const float*)d_in[4];
  const float* proj_w = (const float*)d_in[5];
  const float* proj_b = (const float*)d_in[6];
  float* out = (float*)d_out;

  // Workspace (42.0 MB; 43.6 MB proven available in R1). Same layout as R14.
  char* w = (char*)d_ws;
  float* xavg = (float*)w;                       // 4,718,592
  short* Xh   = (short*)(w + 4718592);
  short* Ah   = (short*)(w + 9437184);
  float* part_o = (float*)w;                     // 28,311,552 (aliases above)
  short* Wth  = (short*)(w + 28311552);          // 524,288
  short* Wtl  = (short*)(w + 28835840);
  short* Qhi  = (short*)(w + 29360128);          // 2,359,296
  short* Khi  = (short*)(w + 31719424);
  short* Vhi  = (short*)(w + 34078720);
  float* part_l = (float*)(w + 36438016);        // 884,736
  short* Zh   = (short*)(w + 37322752);
  short* Zl   = (short*)(w + 39682048);          // ends 42,041,344

  const float qscale = 0.17677669529663689f * 1.4426950408889634f; // d^-0.5*log2(e)

  pool_kernel<<<BATCH * DIMC, 256, 0, stream>>>(x, xavg);
  conv_all<<<704, 256, 0, stream>>>(x, xavg, q_w, kv_w, proj_w,
                                    Xh, Ah, Wth, Wtl);
  gemm_qkv_hi<<<dim3(36, 24, 2), 128, 0, stream>>>(Wth, Wtl, q_b, kv_b,
                                                   Xh, Ah, Qhi, Khi, Vhi, qscale);
  attn_mfma<<<dim3(16 * 36, NSPLIT), 128, 0, stream>>>(Qhi, Khi, Vhi, part_o, part_l);
  attn_merge<<<256, 288, 0, stream>>>(part_o, part_l, Zh, Zl);
  gemm_proj<<<dim3(36, 8, 2), 128, 0, stream>>>(Wth + 196608, Wtl + 196608, proj_b,
                                                Zh, Zl, out);
}

// Round 16
// 157.016 us; speedup vs baseline: 1.0399x; 1.0399x over previous
//
#include <hip/hip_runtime.h>
#include <hip/hip_bf16.h>
#include <cstdint>

// Problem constants
#define DIMC  256
#define NH    8
#define HD    32
#define NPIX  2304       // 48*48
#define BATCH 2
#define NSPLIT 6
#define KPS   384        // keys per split (2304/6)
#define KT    32
#define NT    (KPS / KT) // 12

typedef short s16x8 __attribute__((ext_vector_type(8)));
typedef short s16x4 __attribute__((ext_vector_type(4)));
typedef float f32x4 __attribute__((ext_vector_type(4)));

#define MFMA32(A,B,C) __builtin_amdgcn_mfma_f32_16x16x32_bf16(A,B,C,0,0,0)

// RNA (round-to-nearest-away) bf16 helpers: 1 VALU each.
__device__ inline uint32_t rnau(float x) { return __float_as_uint(x) + 0x8000u; }
__device__ inline uint32_t pk2(uint32_t l_, uint32_t h_) {
  return __builtin_amdgcn_perm(h_, l_, 0x07060302u);
}
__device__ inline float hif(uint32_t a) { return __uint_as_float(a & 0xffff0000u); }

// ---------------------------------------------------------------------------
// Pool: x_avg = (x + box3/9 + box5/25 + box7/49)/4, zero-pad, include_pad
// ---------------------------------------------------------------------------
__global__ __launch_bounds__(256) void pool_kernel(const float* __restrict__ x,
                                                   float* __restrict__ xavg) {
  const int plane = blockIdx.x;
  const float* xp = x + (size_t)plane * NPIX;
  __shared__ float sx[NPIX];
  __shared__ float h3[NPIX], h5[NPIX], h7[NPIX];
  const int t = threadIdx.x;
#pragma unroll
  for (int r = 0; r < 9; ++r) sx[r * 256 + t] = xp[r * 256 + t];
  __syncthreads();
#pragma unroll
  for (int r = 0; r < 9; ++r) {
    int p = r * 256 + t;
    int i = p / 48, j = p - i * 48;
    float a3 = 0.f, a5 = 0.f, a7 = 0.f;
#pragma unroll
    for (int dj = -3; dj <= 3; ++dj) {
      int jj = j + dj;
      if (jj < 0 || jj >= 48) continue;
      float v = sx[i * 48 + jj];
      a7 += v;
      if (dj >= -2 && dj <= 2) a5 += v;
      if (dj >= -1 && dj <= 1) a3 += v;
    }
    h3[p] = a3; h5[p] = a5; h7[p] = a7;
  }
  __syncthreads();
#pragma unroll
  for (int r = 0; r < 9; ++r) {
    int p = r * 256 + t;
    int i = p / 48, j = p - i * 48;
    float b3 = 0.f, b5 = 0.f, b7 = 0.f;
#pragma unroll
    for (int di = -3; di <= 3; ++di) {
      int ii = i + di;
      if (ii < 0 || ii >= 48) continue;
      int q = ii * 48 + j;
      b7 += h7[q];
      if (di >= -2 && di <= 2) b5 += h5[q];
      if (di >= -1 && di <= 1) b3 += h3[q];
    }
    xavg[(size_t)plane * NPIX + p] =
        0.25f * (sx[p] + b3 * (1.f / 9.f) + b5 * (1.f / 25.f) + b7 * (1.f / 49.f));
  }
}

// ---------------------------------------------------------------------------
// Fused converts: blocks 0..287 tconv(x), 288..575 tconv(xavg), 576..703 wconv
// tconv: HI-ONLY. wconv keeps hi+lo. UNCHANGED from R14.
// ---------------------------------------------------------------------------
__global__ __launch_bounds__(256) void conv_all(
    const float* __restrict__ x, const float* __restrict__ xavg,
    const float* __restrict__ qw, const float* __restrict__ kvw,
    const float* __restrict__ pw_,
    short* __restrict__ Xh, short* __restrict__ Ah,
    short* __restrict__ Wth, short* __restrict__ Wtl) {
  const int bx = blockIdx.x;
  const int t = threadIdx.x;
  if (bx < 576) {
    const float* src = (bx < 288) ? x : xavg;
    short* dhi = (bx < 288) ? Xh : Ah;
    const int bb = (bx < 288) ? bx : bx - 288;
    const int n0 = (bb % 36) * 64, c0 = ((bb / 36) & 3) * 64, b = bb / 144;
    __shared__ __align__(16) float T[64][68];
    {
      const int c = t >> 2, n4 = (t & 3) * 16;
      const float* sp = src + ((size_t)b * DIMC + c0 + c) * NPIX + n0 + n4;
#pragma unroll
      for (int i2 = 0; i2 < 4; ++i2)
        *(f32x4*)&T[c][n4 + i2 * 4] = *(const f32x4*)(sp + i2 * 4);
    }
    __syncthreads();
    {
      const int n = t >> 2, c4 = (t & 3) * 16;
      float v[16];
#pragma unroll
      for (int i = 0; i < 16; ++i) v[i] = T[c4 + i][n];
      uint32_t a[16];
#pragma unroll
      for (int i = 0; i < 16; ++i) a[i] = rnau(v[i]);
      union { s16x8 s; uint32_t u[4]; } H0, H1;
#pragma unroll
      for (int j = 0; j < 4; ++j) {
        H0.u[j] = pk2(a[2 * j], a[2 * j + 1]);
        H1.u[j] = pk2(a[8 + 2 * j], a[8 + 2 * j + 1]);
      }
      const size_t off = ((size_t)b * NPIX + n0 + n) * DIMC + c0 + c4;
      *(s16x8*)(dhi + off) = H0.s; *(s16x8*)(dhi + off + 8) = H1.s;
    }
  } else {
    const int idx = ((bx - 576) * 256 + t) * 8;
    const float* s;
    int off;
    if (idx < 65536)       { s = qw;  off = idx; }
    else if (idx < 196608) { s = kvw; off = idx - 65536; }
    else                   { s = pw_; off = idx - 196608; }
    f32x4 x0 = *(const f32x4*)(s + off);
    f32x4 x1 = *(const f32x4*)(s + off + 4);
    float v[8] = {x0[0], x0[1], x0[2], x0[3], x1[0], x1[1], x1[2], x1[3]};
    uint32_t a[8], al[8];
#pragma unroll
    for (int i = 0; i < 8; ++i) a[i] = rnau(v[i]);
#pragma unroll
    for (int i = 0; i < 8; ++i) al[i] = rnau(v[i] - hif(a[i]));
    union { s16x8 s; uint32_t u[4]; } H, L;
#pragma unroll
    for (int j = 0; j < 4; ++j) {
      H.u[j] = pk2(a[2 * j], a[2 * j + 1]);
      L.u[j] = pk2(al[2 * j], al[2 * j + 1]);
    }
    *(s16x8*)(Wth + idx) = H.s;
    *(s16x8*)(Wtl + idx) = L.s;
  }
}

// ---------------------------------------------------------------------------
// PROJ GEMM, fully specialized: B-input Zh HI-ONLY, 2 MFMAs
// (Wh*Zh + Wl*Zh — weight hi/lo kept, z_lo term dropped; z_lo <= 2^-9
// relative, ~0.5-1e-3 absolute after contraction). fp32 out + bias.
// ---------------------------------------------------------------------------
__global__ __launch_bounds__(128) void gemm_proj_hi(
    const short* __restrict__ Wh, const short* __restrict__ Wl,
    const float* __restrict__ bias,
    const short* __restrict__ Zh,
    float* __restrict__ out) {
  __shared__ __align__(16) float Cl[32][68];
  const int n0 = blockIdx.x * 64;
  const int o0 = blockIdx.y * 32;
  const int b  = blockIdx.z;
  const int tid = threadIdx.x;
  const int wave = tid >> 6, lane = tid & 63;
  const int g = lane >> 4, q = lane & 15;

  const short* wph = Wh + ((o0 + wave * 16 + q) * DIMC + g * 8);
  const short* wpl = Wl + ((o0 + wave * 16 + q) * DIMC + g * 8);
  const short* iph = Zh + ((size_t)(b * NPIX + n0 + q) * DIMC + g * 8);

  f32x4 acc[4] = {{0,0,0,0},{0,0,0,0},{0,0,0,0},{0,0,0,0}};
#pragma unroll
  for (int c0 = 0; c0 < DIMC; c0 += 32) {
    s16x8 ah = *(const s16x8*)(wph + c0);
    s16x8 al = *(const s16x8*)(wpl + c0);
#pragma unroll
    for (int st = 0; st < 4; ++st) {
      s16x8 bh_ = *(const s16x8*)(iph + (size_t)st * 16 * DIMC + c0);
      acc[st] = MFMA32(ah, bh_, acc[st]);
      acc[st] = MFMA32(al, bh_, acc[st]);
    }
  }
#pragma unroll
  for (int st = 0; st < 4; ++st)
#pragma unroll
    for (int r = 0; r < 4; ++r)
      Cl[wave * 16 + g * 4 + r][st * 16 + q] = acc[st][r];
  __syncthreads();

  const int o = tid >> 2, nc = (tid & 3) * 16;
  const float bv = bias[o0 + o];
  float* op = out + ((size_t)b * DIMC + o0 + o) * NPIX + n0 + nc;
#pragma unroll
  for (int i2 = 0; i2 < 4; ++i2) {
    f32x4 v = *(const f32x4*)&Cl[o][nc + i2 * 4];
    v[0] += bv; v[1] += bv; v[2] += bv; v[3] += bv;
    *(f32x4*)(op + i2 * 4) = v;
  }
}

// ---------------------------------------------------------------------------
// QKV GEMM, fully specialized hi-only inputs, 2 MFMAs. UNCHANGED from R13.
// ---------------------------------------------------------------------------
__global__ __launch_bounds__(128) void gemm_qkv_hi(
    const short* __restrict__ Wth, const short* __restrict__ Wtl,
    const float* __restrict__ q_b, const float* __restrict__ kv_b,
    const short* __restrict__ Xh, const short* __restrict__ Ah,
    short* __restrict__ Qhi, short* __restrict__ Khi, short* __restrict__ Vhi,
    float qscale) {
  __shared__ __align__(16) float Cl[32][68];
  const int by = blockIdx.y;
  const bool isQ = (by < 8);
  const int o0 = isQ ? by * 32 : (by - 8) * 32;
  const short* Wh = isQ ? Wth : Wth + 65536;
  const short* Wl = isQ ? Wtl : Wtl + 65536;
  const float* bias = isQ ? q_b : kv_b;
  const short* Inh = isQ ? Xh : Ah;
  const float scale = isQ ? qscale : 1.0f;
  short* d1 = isQ ? Qhi : Khi;   // used when o0 < 256 (Q or K)
  const int n0 = blockIdx.x * 64;
  const int b  = blockIdx.z;

  const int tid = threadIdx.x;
  const int wave = tid >> 6, lane = tid & 63;
  const int g = lane >> 4, q = lane & 15;

  const short* wph = Wh + ((o0 + wave * 16 + q) * DIMC + g * 8);
  const short* wpl = Wl + ((o0 + wave * 16 + q) * DIMC + g * 8);
  const short* iph = Inh + ((size_t)(b * NPIX + n0 + q) * DIMC + g * 8);

  f32x4 acc[4] = {{0,0,0,0},{0,0,0,0},{0,0,0,0},{0,0,0,0}};
#pragma unroll
  for (int c0 = 0; c0 < DIMC; c0 += 32) {
    s16x8 ah = *(const s16x8*)(wph + c0);
    s16x8 al = *(const s16x8*)(wpl + c0);
#pragma unroll
    for (int st = 0; st < 4; ++st) {
      s16x8 bh_ = *(const s16x8*)(iph + (size_t)st * 16 * DIMC + c0);
      acc[st] = MFMA32(ah, bh_, acc[st]);
      acc[st] = MFMA32(al, bh_, acc[st]);
    }
  }
#pragma unroll
  for (int st = 0; st < 4; ++st)
#pragma unroll
    for (int r = 0; r < 4; ++r)
      Cl[wave * 16 + g * 4 + r][st * 16 + q] = acc[st][r];
  __syncthreads();

  if (o0 < 256) {
    // Q or K: (C+bias)*scale, hi-only, layout [bh][n][32]
    const int n = tid >> 1, oq = tid & 1;
    const int h = o0 >> 5;
    const float* bp = bias + o0 + oq * 16;
    float v[16];
#pragma unroll
    for (int i = 0; i < 16; ++i) v[i] = (Cl[oq * 16 + i][n] + bp[i]) * scale;
    uint32_t a[16];
#pragma unroll
    for (int i = 0; i < 16; ++i) a[i] = rnau(v[i]);
    union { s16x8 s; uint32_t u[4]; } H0, H1;
#pragma unroll
    for (int j = 0; j < 4; ++j) {
      H0.u[j] = pk2(a[2 * j], a[2 * j + 1]);
      H1.u[j] = pk2(a[8 + 2 * j], a[8 + 2 * j + 1]);
    }
    const size_t off = ((size_t)((b * 8 + h) * NPIX + n0 + n)) * HD + oq * 16;
    *(s16x8*)(d1 + off) = H0.s; *(s16x8*)(d1 + off + 8) = H1.s;
  } else {
    // V hi-only: dst [bh][d][n]
    const int o = tid >> 2, nc = (tid & 3) * 16;
    const int h = (o0 - 256) >> 5;
    const float bv = bias[o0 + o];
    float v[16];
#pragma unroll
    for (int i2 = 0; i2 < 4; ++i2) {
      f32x4 t4 = *(const f32x4*)&Cl[o][nc + i2 * 4];
      v[i2 * 4 + 0] = t4[0] + bv; v[i2 * 4 + 1] = t4[1] + bv;
      v[i2 * 4 + 2] = t4[2] + bv; v[i2 * 4 + 3] = t4[3] + bv;
    }
    uint32_t a[16];
#pragma unroll
    for (int i = 0; i < 16; ++i) a[i] = rnau(v[i]);
    union { s16x8 s; uint32_t u[4]; } H0, H1;
#pragma unroll
    for (int j = 0; j < 4; ++j) {
      H0.u[j] = pk2(a[2 * j], a[2 * j + 1]);
      H1.u[j] = pk2(a[8 + 2 * j], a[8 + 2 * j + 1]);
    }
    const size_t off = ((size_t)((b * 8 + h) * HD + o)) * NPIX + n0 + nc;
    *(s16x8*)(Vhi + off) = H0.s; *(s16x8*)(Vhi + off + 8) = H1.s;
  }
}

// ---------------------------------------------------------------------------
// MFMA flash attention — R15 body (ring prefetch + MFMA l-sum; both verified
// bit-exact vs R13). UNCHANGED.
// ---------------------------------------------------------------------------
__global__ __launch_bounds__(128) void attn_mfma(
    const short* __restrict__ Qhi,   // [bh][n][32]
    const short* __restrict__ Khi,   // [bh][n][32]
    const short* __restrict__ Vhi,   // [bh][32][N]
    float* __restrict__ part_o,      // [row][NSPLIT][32]
    float* __restrict__ part_l) {    // [row][NSPLIT]
  const int sb = blockIdx.x;        // 0..575 = 16 bh * 36 qb
  const int bh = sb / 36;
  const int qb = sb % 36;           // 64-row block
  const int split = blockIdx.y;     // 0..NSPLIT-1
  const int tid = threadIdx.x;
  const int wave = tid >> 6, lane = tid & 63;
  const int g = lane >> 4, q = lane & 15;
  const int base = qb * 64 + wave * 32;

  __shared__ __align__(16) short Plds[2][2][16 * 40];
  short* pwA = &Plds[wave][0][0];
  short* pwB = &Plds[wave][1][0];

  const size_t qoff = ((size_t)bh * NPIX + base + q) * HD + g * 8;
  const s16x8 qhA = *(const s16x8*)(Qhi + qoff);
  const s16x8 qhB = *(const s16x8*)(Qhi + qoff + 16 * HD);

  const short* kp = Khi + ((size_t)bh * NPIX + split * KPS + q) * HD + g * 8;
  const short* vp = Vhi + ((size_t)bh * HD + q) * NPIX + split * KPS + g * 8;

  const f32x4 Z4 = {0.f, 0.f, 0.f, 0.f};
  f32x4 OA0 = Z4, OA1 = Z4, OB0 = Z4, OB1 = Z4;
  f32x4 LA = Z4, LB = Z4;
  s16x8 kb[3][2], vb[3][2], pfA, pfB, vp0, vp1;

  union { s16x8 s; uint32_t u[4]; } ONE;
  ONE.u[0] = 0x3F803F80u; ONE.u[1] = 0x3F803F80u;
  ONE.u[2] = 0x3F803F80u; ONE.u[3] = 0x3F803F80u;
  const s16x8 ones = ONE.s;

  kb[0][0] = *(const s16x8*)(kp);
  kb[0][1] = *(const s16x8*)(kp + 16 * HD);
  vb[0][0] = *(const s16x8*)(vp);
  vb[0][1] = *(const s16x8*)(vp + 16 * NPIX);
  kb[1][0] = *(const s16x8*)(kp + KT * HD);
  kb[1][1] = *(const s16x8*)(kp + KT * HD + 16 * HD);
  vb[1][0] = *(const s16x8*)(vp + KT);
  vb[1][1] = *(const s16x8*)(vp + KT + 16 * NPIX);

#pragma unroll
  for (int t = 0; t < NT; ++t) {
    const int cur = t % 3;
    if (t + 2 < NT) {
      const int nx2 = (t + 2) % 3;
      const short* kpn = kp + (t + 2) * (KT * HD);
      const short* vpn = vp + (t + 2) * KT;
      kb[nx2][0] = *(const s16x8*)(kpn);
      kb[nx2][1] = *(const s16x8*)(kpn + 16 * HD);
      vb[nx2][0] = *(const s16x8*)(vpn);
      vb[nx2][1] = *(const s16x8*)(vpn + 16 * NPIX);
    }
    f32x4 SA0 = MFMA32(kb[cur][0], qhA, Z4);
    f32x4 SA1 = MFMA32(kb[cur][1], qhA, Z4);
    f32x4 SB0 = MFMA32(kb[cur][0], qhB, Z4);
    f32x4 SB1 = MFMA32(kb[cur][1], qhB, Z4);
    if (t > 0) {
      OA0 = MFMA32(vp0, pfA, OA0);
      OA1 = MFMA32(vp1, pfA, OA1);
      OB0 = MFMA32(vp0, pfB, OB0);
      OB1 = MFMA32(vp1, pfB, OB1);
      LA  = MFMA32(ones, pfA, LA);
      LB  = MFMA32(ones, pfB, LB);
    }
    {
      f32x4 p0, p1;
#pragma unroll
      for (int r = 0; r < 4; ++r) { p0[r] = exp2f(SA0[r]); p1[r] = exp2f(SA1[r]); }
      uint2 w0, w1;
      w0.x = pk2(rnau(p0[0]), rnau(p0[1])); w0.y = pk2(rnau(p0[2]), rnau(p0[3]));
      w1.x = pk2(rnau(p1[0]), rnau(p1[1])); w1.y = pk2(rnau(p1[2]), rnau(p1[3]));
      *(uint2*)&pwA[q * 40 + g * 4] = w0;
      *(uint2*)&pwA[q * 40 + 16 + g * 4] = w1;
    }
    {
      f32x4 p0, p1;
#pragma unroll
      for (int r = 0; r < 4; ++r) { p0[r] = exp2f(SB0[r]); p1[r] = exp2f(SB1[r]); }
      uint2 w0, w1;
      w0.x = pk2(rnau(p0[0]), rnau(p0[1])); w0.y = pk2(rnau(p0[2]), rnau(p0[3]));
      w1.x = pk2(rnau(p1[0]), rnau(p1[1])); w1.y = pk2(rnau(p1[2]), rnau(p1[3]));
      *(uint2*)&pwB[q * 40 + g * 4] = w0;
      *(uint2*)&pwB[q * 40 + 16 + g * 4] = w1;
    }
    vp0 = vb[cur][0]; vp1 = vb[cur][1];
    pfA = *(const s16x8*)&pwA[q * 40 + g * 8];
    pfB = *(const s16x8*)&pwB[q * 40 + g * 8];
  }
  OA0 = MFMA32(vp0, pfA, OA0);
  OA1 = MFMA32(vp1, pfA, OA1);
  OB0 = MFMA32(vp0, pfB, OB0);
  OB1 = MFMA32(vp1, pfB, OB1);
  LA  = MFMA32(ones, pfA, LA);
  LB  = MFMA32(ones, pfB, LB);

  const int rowA = bh * NPIX + base + q;
  const int rowB = rowA + 16;
  float* poA = part_o + ((size_t)rowA * NSPLIT + split) * HD;
  float* poB = part_o + ((size_t)rowB * NSPLIT + split) * HD;
  *(f32x4*)(poA + g * 4) = OA0;
  *(f32x4*)(poA + 16 + g * 4) = OA1;
  *(f32x4*)(poB + g * 4) = OB0;
  *(f32x4*)(poB + 16 + g * 4) = OB1;
  if (g == 0) {
    part_l[(size_t)rowA * NSPLIT + split] = LA[0];
    part_l[(size_t)rowB * NSPLIT + split] = LB[0];
  }
}

// ---------------------------------------------------------------------------
// Merge splits, emit SCRAMBLED z HI-ONLY [b][p][256] (Zl dropped — proj is
// 2-MFMA hi-B now). 256 blocks.
// ---------------------------------------------------------------------------
__global__ __launch_bounds__(288) void attn_merge(const float* __restrict__ part_o,
                                                  const float* __restrict__ part_l,
                                                  short* __restrict__ zh) {
  const int blk = blockIdx.x;          // 256 = 16 bh * 16
  const int bh = blk >> 4;
  const int n0 = (blk & 15) * 144;
  const int head = bh & 7, b = bh >> 3;
  const int t = threadIdx.x;
  __shared__ __align__(16) float T[144][36];
  {
    const int r = t >> 1, uh = (t & 1) * 4;   // r in 0..143
    const int idx = bh * NPIX + n0 + r;
    const float* pl = part_l + (size_t)idx * NSPLIT;
    float L = 0.f;
#pragma unroll
    for (int s = 0; s < NSPLIT; ++s) L += pl[s];
    const float inv = 1.f / L;
    const float* po = part_o + (size_t)idx * (NSPLIT * HD);
#pragma unroll
    for (int u = 0; u < 4; ++u) {
      f32x4 v = {0.f, 0.f, 0.f, 0.f};
#pragma unroll
      for (int s = 0; s < NSPLIT; ++s)
        v += *(const f32x4*)(po + s * HD + (uh + u) * 4);
      v[0] *= inv; v[1] *= inv; v[2] *= inv; v[3] *= inv;
      *(f32x4*)&T[r][(uh + u) * 4] = v;
    }
  }
  __syncthreads();
  {
    const int r9 = t / 32, dd = t & 31;    // r9 in 0..8
    const int p = r9 * 256 + head * HD + dd;
    const int c0 = n0 / 9;                  // 16 channels per chunk
    float v[16];
#pragma unroll
    for (int j = 0; j < 16; ++j) v[j] = T[9 * j + r9][dd];
    uint32_t a[16];
#pragma unroll
    for (int j = 0; j < 16; ++j) a[j] = rnau(v[j]);
    const size_t off = ((size_t)b * NPIX + p) * DIMC + c0;
#pragma unroll
    for (int c8 = 0; c8 < 2; ++c8) {
      union { s16x8 s; uint32_t u[4]; } H;
#pragma unroll
      for (int j = 0; j < 4; ++j)
        H.u[j] = pk2(a[c8 * 8 + 2 * j], a[c8 * 8 + 2 * j + 1]);
      *(s16x8*)(zh + off + c8 * 8) = H.s;
    }
  }
}

// ---------------------------------------------------------------------------
extern "C" void kernel_launch(void* const* d_in, const int* in_sizes, int n_in,
                              void* d_out, int out_size, void* d_ws, size_t ws_size,
                              hipStream_t stream) {
  const float* x      = (const float*)d_in[0];
  const float* q_w    = (const float*)d_in[1];
  const float* q_b    = (const float*)d_in[2];
  const float* kv_w   = (const float*)d_in[3];
  const float* kv_b   = (const float*)d_in[4];
  const float* proj_w = (const float*)d_in[5];
  const float* proj_b = (const float*)d_in[6];
  float* out = (float*)d_out;

  // Workspace (<=42.0 MB; 43.6 MB proven available). Same offsets as R15
  // (Zl slot now unused).
  char* w = (char*)d_ws;
  float* xavg = (float*)w;                       // 4,718,592
  short* Xh   = (short*)(w + 4718592);
  short* Ah   = (short*)(w + 9437184);
  float* part_o = (float*)w;                     // 28,311,552 (aliases above)
  short* Wth  = (short*)(w + 28311552);          // 524,288
  short* Wtl  = (short*)(w + 28835840);
  short* Qhi  = (short*)(w + 29360128);          // 2,359,296
  short* Khi  = (short*)(w + 31719424);
  short* Vhi  = (short*)(w + 34078720);
  float* part_l = (float*)(w + 36438016);        // 884,736
  short* Zh   = (short*)(w + 37322752);          // 2,359,296

  const float qscale = 0.17677669529663689f * 1.4426950408889634f; // d^-0.5*log2(e)

  pool_kernel<<<BATCH * DIMC, 256, 0, stream>>>(x, xavg);
  conv_all<<<704, 256, 0, stream>>>(x, xavg, q_w, kv_w, proj_w,
                                    Xh, Ah, Wth, Wtl);
  gemm_qkv_hi<<<dim3(36, 24, 2), 128, 0, stream>>>(Wth, Wtl, q_b, kv_b,
                                                   Xh, Ah, Qhi, Khi, Vhi, qscale);
  attn_mfma<<<dim3(16 * 36, NSPLIT), 128, 0, stream>>>(Qhi, Khi, Vhi, part_o, part_l);
  attn_merge<<<256, 288, 0, stream>>>(part_o, part_l, Zh);
  gemm_proj_hi<<<dim3(36, 8, 2), 128, 0, stream>>>(Wth + 196608, Wtl + 196608,
                                                   proj_b, Zh, out);
}

// Round 17
// 151.157 us; speedup vs baseline: 1.0802x; 1.0388x over previous
//
#include <hip/hip_runtime.h>
#include <hip/hip_bf16.h>
#include <cstdint>

// Problem constants
#define DIMC  256
#define NH    8
#define HD    32
#define NPIX  2304       // 48*48
#define BATCH 2
#define NSPLIT 6
#define KPS   384        // keys per split (2304/6)
#define KT    32
#define NT    (KPS / KT) // 12

typedef short s16x8 __attribute__((ext_vector_type(8)));
typedef short s16x4 __attribute__((ext_vector_type(4)));
typedef float f32x4 __attribute__((ext_vector_type(4)));

#define MFMA32(A,B,C) __builtin_amdgcn_mfma_f32_16x16x32_bf16(A,B,C,0,0,0)

// RNA (round-to-nearest-away) bf16 helpers: 1 VALU each.
__device__ inline uint32_t rnau(float x) { return __float_as_uint(x) + 0x8000u; }
__device__ inline uint32_t pk2(uint32_t l_, uint32_t h_) {
  return __builtin_amdgcn_perm(h_, l_, 0x07060302u);
}

// ---------------------------------------------------------------------------
// Pool: x_avg = (x + box3/9 + box5/25 + box7/49)/4, zero-pad, include_pad
// ---------------------------------------------------------------------------
__global__ __launch_bounds__(256) void pool_kernel(const float* __restrict__ x,
                                                   float* __restrict__ xavg) {
  const int plane = blockIdx.x;
  const float* xp = x + (size_t)plane * NPIX;
  __shared__ float sx[NPIX];
  __shared__ float h3[NPIX], h5[NPIX], h7[NPIX];
  const int t = threadIdx.x;
#pragma unroll
  for (int r = 0; r < 9; ++r) sx[r * 256 + t] = xp[r * 256 + t];
  __syncthreads();
#pragma unroll
  for (int r = 0; r < 9; ++r) {
    int p = r * 256 + t;
    int i = p / 48, j = p - i * 48;
    float a3 = 0.f, a5 = 0.f, a7 = 0.f;
#pragma unroll
    for (int dj = -3; dj <= 3; ++dj) {
      int jj = j + dj;
      if (jj < 0 || jj >= 48) continue;
      float v = sx[i * 48 + jj];
      a7 += v;
      if (dj >= -2 && dj <= 2) a5 += v;
      if (dj >= -1 && dj <= 1) a3 += v;
    }
    h3[p] = a3; h5[p] = a5; h7[p] = a7;
  }
  __syncthreads();
#pragma unroll
  for (int r = 0; r < 9; ++r) {
    int p = r * 256 + t;
    int i = p / 48, j = p - i * 48;
    float b3 = 0.f, b5 = 0.f, b7 = 0.f;
#pragma unroll
    for (int di = -3; di <= 3; ++di) {
      int ii = i + di;
      if (ii < 0 || ii >= 48) continue;
      int q = ii * 48 + j;
      b7 += h7[q];
      if (di >= -2 && di <= 2) b5 += h5[q];
      if (di >= -1 && di <= 1) b3 += h3[q];
    }
    xavg[(size_t)plane * NPIX + p] =
        0.25f * (sx[p] + b3 * (1.f / 9.f) + b5 * (1.f / 25.f) + b7 * (1.f / 49.f));
  }
}

// ---------------------------------------------------------------------------
// Fused converts: blocks 0..287 tconv(x), 288..575 tconv(xavg), 576..703 wconv
// tconv: HI-ONLY. wconv: HI-ONLY now too (w_lo dropped — twin of the z_lo
// drop which measured zero absmax effect in R16).
// ---------------------------------------------------------------------------
__global__ __launch_bounds__(256) void conv_all(
    const float* __restrict__ x, const float* __restrict__ xavg,
    const float* __restrict__ qw, const float* __restrict__ kvw,
    const float* __restrict__ pw_,
    short* __restrict__ Xh, short* __restrict__ Ah,
    short* __restrict__ Wth) {
  const int bx = blockIdx.x;
  const int t = threadIdx.x;
  if (bx < 576) {
    const float* src = (bx < 288) ? x : xavg;
    short* dhi = (bx < 288) ? Xh : Ah;
    const int bb = (bx < 288) ? bx : bx - 288;
    const int n0 = (bb % 36) * 64, c0 = ((bb / 36) & 3) * 64, b = bb / 144;
    __shared__ __align__(16) float T[64][68];
    {
      const int c = t >> 2, n4 = (t & 3) * 16;
      const float* sp = src + ((size_t)b * DIMC + c0 + c) * NPIX + n0 + n4;
#pragma unroll
      for (int i2 = 0; i2 < 4; ++i2)
        *(f32x4*)&T[c][n4 + i2 * 4] = *(const f32x4*)(sp + i2 * 4);
    }
    __syncthreads();
    {
      const int n = t >> 2, c4 = (t & 3) * 16;
      float v[16];
#pragma unroll
      for (int i = 0; i < 16; ++i) v[i] = T[c4 + i][n];
      uint32_t a[16];
#pragma unroll
      for (int i = 0; i < 16; ++i) a[i] = rnau(v[i]);
      union { s16x8 s; uint32_t u[4]; } H0, H1;
#pragma unroll
      for (int j = 0; j < 4; ++j) {
        H0.u[j] = pk2(a[2 * j], a[2 * j + 1]);
        H1.u[j] = pk2(a[8 + 2 * j], a[8 + 2 * j + 1]);
      }
      const size_t off = ((size_t)b * NPIX + n0 + n) * DIMC + c0 + c4;
      *(s16x8*)(dhi + off) = H0.s; *(s16x8*)(dhi + off + 8) = H1.s;
    }
  } else {
    const int idx = ((bx - 576) * 256 + t) * 8;
    const float* s;
    int off;
    if (idx < 65536)       { s = qw;  off = idx; }
    else if (idx < 196608) { s = kvw; off = idx - 65536; }
    else                   { s = pw_; off = idx - 196608; }
    f32x4 x0 = *(const f32x4*)(s + off);
    f32x4 x1 = *(const f32x4*)(s + off + 4);
    float v[8] = {x0[0], x0[1], x0[2], x0[3], x1[0], x1[1], x1[2], x1[3]};
    uint32_t a[8];
#pragma unroll
    for (int i = 0; i < 8; ++i) a[i] = rnau(v[i]);
    union { s16x8 s; uint32_t u[4]; } H;
#pragma unroll
    for (int j = 0; j < 4; ++j) H.u[j] = pk2(a[2 * j], a[2 * j + 1]);
    *(s16x8*)(Wth + idx) = H.s;
  }
}

// ---------------------------------------------------------------------------
// PROJ GEMM: single MFMA/tile (Wh*Zh). fp32 out + bias.
// ---------------------------------------------------------------------------
__global__ __launch_bounds__(128) void gemm_proj_hi(
    const short* __restrict__ Wh,
    const float* __restrict__ bias,
    const short* __restrict__ Zh,
    float* __restrict__ out) {
  __shared__ __align__(16) float Cl[32][68];
  const int n0 = blockIdx.x * 64;
  const int o0 = blockIdx.y * 32;
  const int b  = blockIdx.z;
  const int tid = threadIdx.x;
  const int wave = tid >> 6, lane = tid & 63;
  const int g = lane >> 4, q = lane & 15;

  const short* wph = Wh + ((o0 + wave * 16 + q) * DIMC + g * 8);
  const short* iph = Zh + ((size_t)(b * NPIX + n0 + q) * DIMC + g * 8);

  f32x4 acc[4] = {{0,0,0,0},{0,0,0,0},{0,0,0,0},{0,0,0,0}};
#pragma unroll
  for (int c0 = 0; c0 < DIMC; c0 += 32) {
    s16x8 ah = *(const s16x8*)(wph + c0);
#pragma unroll
    for (int st = 0; st < 4; ++st) {
      s16x8 bh_ = *(const s16x8*)(iph + (size_t)st * 16 * DIMC + c0);
      acc[st] = MFMA32(ah, bh_, acc[st]);
    }
  }
#pragma unroll
  for (int st = 0; st < 4; ++st)
#pragma unroll
    for (int r = 0; r < 4; ++r)
      Cl[wave * 16 + g * 4 + r][st * 16 + q] = acc[st][r];
  __syncthreads();

  const int o = tid >> 2, nc = (tid & 3) * 16;
  const float bv = bias[o0 + o];
  float* op = out + ((size_t)b * DIMC + o0 + o) * NPIX + n0 + nc;
#pragma unroll
  for (int i2 = 0; i2 < 4; ++i2) {
    f32x4 v = *(const f32x4*)&Cl[o][nc + i2 * 4];
    v[0] += bv; v[1] += bv; v[2] += bv; v[3] += bv;
    *(f32x4*)(op + i2 * 4) = v;
  }
}

// ---------------------------------------------------------------------------
// QKV GEMM: single MFMA/tile (Wh*Xh). Specialized epilogues unchanged.
// ---------------------------------------------------------------------------
__global__ __launch_bounds__(128) void gemm_qkv_hi(
    const short* __restrict__ Wth,
    const float* __restrict__ q_b, const float* __restrict__ kv_b,
    const short* __restrict__ Xh, const short* __restrict__ Ah,
    short* __restrict__ Qhi, short* __restrict__ Khi, short* __restrict__ Vhi,
    float qscale) {
  __shared__ __align__(16) float Cl[32][68];
  const int by = blockIdx.y;
  const bool isQ = (by < 8);
  const int o0 = isQ ? by * 32 : (by - 8) * 32;
  const short* Wh = isQ ? Wth : Wth + 65536;
  const float* bias = isQ ? q_b : kv_b;
  const short* Inh = isQ ? Xh : Ah;
  const float scale = isQ ? qscale : 1.0f;
  short* d1 = isQ ? Qhi : Khi;   // used when o0 < 256 (Q or K)
  const int n0 = blockIdx.x * 64;
  const int b  = blockIdx.z;

  const int tid = threadIdx.x;
  const int wave = tid >> 6, lane = tid & 63;
  const int g = lane >> 4, q = lane & 15;

  const short* wph = Wh + ((o0 + wave * 16 + q) * DIMC + g * 8);
  const short* iph = Inh + ((size_t)(b * NPIX + n0 + q) * DIMC + g * 8);

  f32x4 acc[4] = {{0,0,0,0},{0,0,0,0},{0,0,0,0},{0,0,0,0}};
#pragma unroll
  for (int c0 = 0; c0 < DIMC; c0 += 32) {
    s16x8 ah = *(const s16x8*)(wph + c0);
#pragma unroll
    for (int st = 0; st < 4; ++st) {
      s16x8 bh_ = *(const s16x8*)(iph + (size_t)st * 16 * DIMC + c0);
      acc[st] = MFMA32(ah, bh_, acc[st]);
    }
  }
#pragma unroll
  for (int st = 0; st < 4; ++st)
#pragma unroll
    for (int r = 0; r < 4; ++r)
      Cl[wave * 16 + g * 4 + r][st * 16 + q] = acc[st][r];
  __syncthreads();

  if (o0 < 256) {
    // Q or K: (C+bias)*scale, hi-only, layout [bh][n][32]
    const int n = tid >> 1, oq = tid & 1;
    const int h = o0 >> 5;
    const float* bp = bias + o0 + oq * 16;
    float v[16];
#pragma unroll
    for (int i = 0; i < 16; ++i) v[i] = (Cl[oq * 16 + i][n] + bp[i]) * scale;
    uint32_t a[16];
#pragma unroll
    for (int i = 0; i < 16; ++i) a[i] = rnau(v[i]);
    union { s16x8 s; uint32_t u[4]; } H0, H1;
#pragma unroll
    for (int j = 0; j < 4; ++j) {
      H0.u[j] = pk2(a[2 * j], a[2 * j + 1]);
      H1.u[j] = pk2(a[8 + 2 * j], a[8 + 2 * j + 1]);
    }
    const size_t off = ((size_t)((b * 8 + h) * NPIX + n0 + n)) * HD + oq * 16;
    *(s16x8*)(d1 + off) = H0.s; *(s16x8*)(d1 + off + 8) = H1.s;
  } else {
    // V hi-only: dst [bh][d][n]
    const int o = tid >> 2, nc = (tid & 3) * 16;
    const int h = (o0 - 256) >> 5;
    const float bv = bias[o0 + o];
    float v[16];
#pragma unroll
    for (int i2 = 0; i2 < 4; ++i2) {
      f32x4 t4 = *(const f32x4*)&Cl[o][nc + i2 * 4];
      v[i2 * 4 + 0] = t4[0] + bv; v[i2 * 4 + 1] = t4[1] + bv;
      v[i2 * 4 + 2] = t4[2] + bv; v[i2 * 4 + 3] = t4[3] + bv;
    }
    uint32_t a[16];
#pragma unroll
    for (int i = 0; i < 16; ++i) a[i] = rnau(v[i]);
    union { s16x8 s; uint32_t u[4]; } H0, H1;
#pragma unroll
    for (int j = 0; j < 4; ++j) {
      H0.u[j] = pk2(a[2 * j], a[2 * j + 1]);
      H1.u[j] = pk2(a[8 + 2 * j], a[8 + 2 * j + 1]);
    }
    const size_t off = ((size_t)((b * 8 + h) * HD + o)) * NPIX + n0 + nc;
    *(s16x8*)(Vhi + off) = H0.s; *(s16x8*)(Vhi + off + 8) = H1.s;
  }
}

// ---------------------------------------------------------------------------
// MFMA flash attention — R15 body (ring prefetch + MFMA l-sum). UNCHANGED.
// ---------------------------------------------------------------------------
__global__ __launch_bounds__(128) void attn_mfma(
    const short* __restrict__ Qhi,   // [bh][n][32]
    const short* __restrict__ Khi,   // [bh][n][32]
    const short* __restrict__ Vhi,   // [bh][32][N]
    float* __restrict__ part_o,      // [row][NSPLIT][32]
    float* __restrict__ part_l) {    // [row][NSPLIT]
  const int sb = blockIdx.x;        // 0..575 = 16 bh * 36 qb
  const int bh = sb / 36;
  const int qb = sb % 36;           // 64-row block
  const int split = blockIdx.y;     // 0..NSPLIT-1
  const int tid = threadIdx.x;
  const int wave = tid >> 6, lane = tid & 63;
  const int g = lane >> 4, q = lane & 15;
  const int base = qb * 64 + wave * 32;

  __shared__ __align__(16) short Plds[2][2][16 * 40];
  short* pwA = &Plds[wave][0][0];
  short* pwB = &Plds[wave][1][0];

  const size_t qoff = ((size_t)bh * NPIX + base + q) * HD + g * 8;
  const s16x8 qhA = *(const s16x8*)(Qhi + qoff);
  const s16x8 qhB = *(const s16x8*)(Qhi + qoff + 16 * HD);

  const short* kp = Khi + ((size_t)bh * NPIX + split * KPS + q) * HD + g * 8;
  const short* vp = Vhi + ((size_t)bh * HD + q) * NPIX + split * KPS + g * 8;

  const f32x4 Z4 = {0.f, 0.f, 0.f, 0.f};
  f32x4 OA0 = Z4, OA1 = Z4, OB0 = Z4, OB1 = Z4;
  f32x4 LA = Z4, LB = Z4;
  s16x8 kb[3][2], vb[3][2], pfA, pfB, vp0, vp1;

  union { s16x8 s; uint32_t u[4]; } ONE;
  ONE.u[0] = 0x3F803F80u; ONE.u[1] = 0x3F803F80u;
  ONE.u[2] = 0x3F803F80u; ONE.u[3] = 0x3F803F80u;
  const s16x8 ones = ONE.s;

  kb[0][0] = *(const s16x8*)(kp);
  kb[0][1] = *(const s16x8*)(kp + 16 * HD);
  vb[0][0] = *(const s16x8*)(vp);
  vb[0][1] = *(const s16x8*)(vp + 16 * NPIX);
  kb[1][0] = *(const s16x8*)(kp + KT * HD);
  kb[1][1] = *(const s16x8*)(kp + KT * HD + 16 * HD);
  vb[1][0] = *(const s16x8*)(vp + KT);
  vb[1][1] = *(const s16x8*)(vp + KT + 16 * NPIX);

#pragma unroll
  for (int t = 0; t < NT; ++t) {
    const int cur = t % 3;
    if (t + 2 < NT) {
      const int nx2 = (t + 2) % 3;
      const short* kpn = kp + (t + 2) * (KT * HD);
      const short* vpn = vp + (t + 2) * KT;
      kb[nx2][0] = *(const s16x8*)(kpn);
      kb[nx2][1] = *(const s16x8*)(kpn + 16 * HD);
      vb[nx2][0] = *(const s16x8*)(vpn);
      vb[nx2][1] = *(const s16x8*)(vpn + 16 * NPIX);
    }
    f32x4 SA0 = MFMA32(kb[cur][0], qhA, Z4);
    f32x4 SA1 = MFMA32(kb[cur][1], qhA, Z4);
    f32x4 SB0 = MFMA32(kb[cur][0], qhB, Z4);
    f32x4 SB1 = MFMA32(kb[cur][1], qhB, Z4);
    if (t > 0) {
      OA0 = MFMA32(vp0, pfA, OA0);
      OA1 = MFMA32(vp1, pfA, OA1);
      OB0 = MFMA32(vp0, pfB, OB0);
      OB1 = MFMA32(vp1, pfB, OB1);
      LA  = MFMA32(ones, pfA, LA);
      LB  = MFMA32(ones, pfB, LB);
    }
    {
      f32x4 p0, p1;
#pragma unroll
      for (int r = 0; r < 4; ++r) { p0[r] = exp2f(SA0[r]); p1[r] = exp2f(SA1[r]); }
      uint2 w0, w1;
      w0.x = pk2(rnau(p0[0]), rnau(p0[1])); w0.y = pk2(rnau(p0[2]), rnau(p0[3]));
      w1.x = pk2(rnau(p1[0]), rnau(p1[1])); w1.y = pk2(rnau(p1[2]), rnau(p1[3]));
      *(uint2*)&pwA[q * 40 + g * 4] = w0;
      *(uint2*)&pwA[q * 40 + 16 + g * 4] = w1;
    }
    {
      f32x4 p0, p1;
#pragma unroll
      for (int r = 0; r < 4; ++r) { p0[r] = exp2f(SB0[r]); p1[r] = exp2f(SB1[r]); }
      uint2 w0, w1;
      w0.x = pk2(rnau(p0[0]), rnau(p0[1])); w0.y = pk2(rnau(p0[2]), rnau(p0[3]));
      w1.x = pk2(rnau(p1[0]), rnau(p1[1])); w1.y = pk2(rnau(p1[2]), rnau(p1[3]));
      *(uint2*)&pwB[q * 40 + g * 4] = w0;
      *(uint2*)&pwB[q * 40 + 16 + g * 4] = w1;
    }
    vp0 = vb[cur][0]; vp1 = vb[cur][1];
    pfA = *(const s16x8*)&pwA[q * 40 + g * 8];
    pfB = *(const s16x8*)&pwB[q * 40 + g * 8];
  }
  OA0 = MFMA32(vp0, pfA, OA0);
  OA1 = MFMA32(vp1, pfA, OA1);
  OB0 = MFMA32(vp0, pfB, OB0);
  OB1 = MFMA32(vp1, pfB, OB1);
  LA  = MFMA32(ones, pfA, LA);
  LB  = MFMA32(ones, pfB, LB);

  const int rowA = bh * NPIX + base + q;
  const int rowB = rowA + 16;
  float* poA = part_o + ((size_t)rowA * NSPLIT + split) * HD;
  float* poB = part_o + ((size_t)rowB * NSPLIT + split) * HD;
  *(f32x4*)(poA + g * 4) = OA0;
  *(f32x4*)(poA + 16 + g * 4) = OA1;
  *(f32x4*)(poB + g * 4) = OB0;
  *(f32x4*)(poB + 16 + g * 4) = OB1;
  if (g == 0) {
    part_l[(size_t)rowA * NSPLIT + split] = LA[0];
    part_l[(size_t)rowB * NSPLIT + split] = LB[0];
  }
}

// ---------------------------------------------------------------------------
// Merge splits, emit SCRAMBLED z HI-ONLY [b][p][256]. 256 blocks. UNCHANGED.
// ---------------------------------------------------------------------------
__global__ __launch_bounds__(288) void attn_merge(const float* __restrict__ part_o,
                                                  const float* __restrict__ part_l,
                                                  short* __restrict__ zh) {
  const int blk = blockIdx.x;          // 256 = 16 bh * 16
  const int bh = blk >> 4;
  const int n0 = (blk & 15) * 144;
  const int head = bh & 7, b = bh >> 3;
  const int t = threadIdx.x;
  __shared__ __align__(16) float T[144][36];
  {
    const int r = t >> 1, uh = (t & 1) * 4;   // r in 0..143
    const int idx = bh * NPIX + n0 + r;
    const float* pl = part_l + (size_t)idx * NSPLIT;
    float L = 0.f;
#pragma unroll
    for (int s = 0; s < NSPLIT; ++s) L += pl[s];
    const float inv = 1.f / L;
    const float* po = part_o + (size_t)idx * (NSPLIT * HD);
#pragma unroll
    for (int u = 0; u < 4; ++u) {
      f32x4 v = {0.f, 0.f, 0.f, 0.f};
#pragma unroll
      for (int s = 0; s < NSPLIT; ++s)
        v += *(const f32x4*)(po + s * HD + (uh + u) * 4);
      v[0] *= inv; v[1] *= inv; v[2] *= inv; v[3] *= inv;
      *(f32x4*)&T[r][(uh + u) * 4] = v;
    }
  }
  __syncthreads();
  {
    const int r9 = t / 32, dd = t & 31;    // r9 in 0..8
    const int p = r9 * 256 + head * HD + dd;
    const int c0 = n0 / 9;                  // 16 channels per chunk
    float v[16];
#pragma unroll
    for (int j = 0; j < 16; ++j) v[j] = T[9 * j + r9][dd];
    uint32_t a[16];
#pragma unroll
    for (int j = 0; j < 16; ++j) a[j] = rnau(v[j]);
    const size_t off = ((size_t)b * NPIX + p) * DIMC + c0;
#pragma unroll
    for (int c8 = 0; c8 < 2; ++c8) {
      union { s16x8 s; uint32_t u[4]; } H;
#pragma unroll
      for (int j = 0; j < 4; ++j)
        H.u[j] = pk2(a[c8 * 8 + 2 * j], a[c8 * 8 + 2 * j + 1]);
      *(s16x8*)(zh + off + c8 * 8) = H.s;
    }
  }
}

// ---------------------------------------------------------------------------
extern "C" void kernel_launch(void* const* d_in, const int* in_sizes, int n_in,
                              void* d_out, int out_size, void* d_ws, size_t ws_size,
                              hipStream_t stream) {
  const float* x      = (const float*)d_in[0];
  const float* q_w    = (const float*)d_in[1];
  const float* q_b    = (const float*)d_in[2];
  const float* kv_w   = (const float*)d_in[3];
  const float* kv_b   = (const float*)d_in[4];
  const float* proj_w = (const float*)d_in[5];
  const float* proj_b = (const float*)d_in[6];
  float* out = (float*)d_out;

  // Workspace (<=42.0 MB; 43.6 MB proven available). Same offsets as R16
  // (Wtl slot now unused).
  char* w = (char*)d_ws;
  float* xavg = (float*)w;                       // 4,718,592
  short* Xh   = (short*)(w + 4718592);
  short* Ah   = (short*)(w + 9437184);
  float* part_o = (float*)w;                     // 28,311,552 (aliases above)
  short* Wth  = (short*)(w + 28311552);          // 524,288
  short* Qhi  = (short*)(w + 29360128);          // 2,359,296
  short* Khi  = (short*)(w + 31719424);
  short* Vhi  = (short*)(w + 34078720);
  float* part_l = (float*)(w + 36438016);        // 884,736
  short* Zh   = (short*)(w + 37322752);          // 2,359,296

  const float qscale = 0.17677669529663689f * 1.4426950408889634f; // d^-0.5*log2(e)

  pool_kernel<<<BATCH * DIMC, 256, 0, stream>>>(x, xavg);
  conv_all<<<704, 256, 0, stream>>>(x, xavg, q_w, kv_w, proj_w, Xh, Ah, Wth);
  gemm_qkv_hi<<<dim3(36, 24, 2), 128, 0, stream>>>(Wth, q_b, kv_b,
                                                   Xh, Ah, Qhi, Khi, Vhi, qscale);
  attn_mfma<<<dim3(16 * 36, NSPLIT), 128, 0, stream>>>(Qhi, Khi, Vhi, part_o, part_l);
  attn_merge<<<256, 288, 0, stream>>>(part_o, part_l, Zh);
  gemm_proj_hi<<<dim3(36, 8, 2), 128, 0, stream>>>(Wth + 196608, proj_b, Zh, out);
}

// Round 18
// 149.475 us; speedup vs baseline: 1.0924x; 1.0112x over previous
//
#include <hip/hip_runtime.h>
#include <hip/hip_bf16.h>
#include <cstdint>

// Problem constants
#define DIMC  256
#define NH    8
#define HD    32
#define NPIX  2304       // 48*48
#define BATCH 2
#define NSPLIT 6
#define KPS   384        // keys per split (2304/6)
#define KT    32
#define NT    (KPS / KT) // 12

typedef short s16x8 __attribute__((ext_vector_type(8)));
typedef short s16x4 __attribute__((ext_vector_type(4)));
typedef float f32x4 __attribute__((ext_vector_type(4)));

#define MFMA32(A,B,C) __builtin_amdgcn_mfma_f32_16x16x32_bf16(A,B,C,0,0,0)

// RNA (round-to-nearest-away) bf16 helpers: 1 VALU each.
__device__ inline uint32_t rnau(float x) { return __float_as_uint(x) + 0x8000u; }
__device__ inline uint32_t pk2(uint32_t l_, uint32_t h_) {
  return __builtin_amdgcn_perm(h_, l_, 0x07060302u);  // lo short=l_, hi short=h_
}

// ---------------------------------------------------------------------------
// Pool: x_avg = (x + box3/9 + box5/25 + box7/49)/4, zero-pad, include_pad
// ---------------------------------------------------------------------------
__global__ __launch_bounds__(256) void pool_kernel(const float* __restrict__ x,
                                                   float* __restrict__ xavg) {
  const int plane = blockIdx.x;
  const float* xp = x + (size_t)plane * NPIX;
  __shared__ float sx[NPIX];
  __shared__ float h3[NPIX], h5[NPIX], h7[NPIX];
  const int t = threadIdx.x;
#pragma unroll
  for (int r = 0; r < 9; ++r) sx[r * 256 + t] = xp[r * 256 + t];
  __syncthreads();
#pragma unroll
  for (int r = 0; r < 9; ++r) {
    int p = r * 256 + t;
    int i = p / 48, j = p - i * 48;
    float a3 = 0.f, a5 = 0.f, a7 = 0.f;
#pragma unroll
    for (int dj = -3; dj <= 3; ++dj) {
      int jj = j + dj;
      if (jj < 0 || jj >= 48) continue;
      float v = sx[i * 48 + jj];
      a7 += v;
      if (dj >= -2 && dj <= 2) a5 += v;
      if (dj >= -1 && dj <= 1) a3 += v;
    }
    h3[p] = a3; h5[p] = a5; h7[p] = a7;
  }
  __syncthreads();
#pragma unroll
  for (int r = 0; r < 9; ++r) {
    int p = r * 256 + t;
    int i = p / 48, j = p - i * 48;
    float b3 = 0.f, b5 = 0.f, b7 = 0.f;
#pragma unroll
    for (int di = -3; di <= 3; ++di) {
      int ii = i + di;
      if (ii < 0 || ii >= 48) continue;
      int q = ii * 48 + j;
      b7 += h7[q];
      if (di >= -2 && di <= 2) b5 += h5[q];
      if (di >= -1 && di <= 1) b3 += h3[q];
    }
    xavg[(size_t)plane * NPIX + p] =
        0.25f * (sx[p] + b3 * (1.f / 9.f) + b5 * (1.f / 25.f) + b7 * (1.f / 49.f));
  }
}

// ---------------------------------------------------------------------------
// Fused converts: blocks 0..287 tconv(x), 288..575 tconv(xavg), 576..703 wconv
// All HI-ONLY (R17-verified). UNCHANGED.
// ---------------------------------------------------------------------------
__global__ __launch_bounds__(256) void conv_all(
    const float* __restrict__ x, const float* __restrict__ xavg,
    const float* __restrict__ qw, const float* __restrict__ kvw,
    const float* __restrict__ pw_,
    short* __restrict__ Xh, short* __restrict__ Ah,
    short* __restrict__ Wth) {
  const int bx = blockIdx.x;
  const int t = threadIdx.x;
  if (bx < 576) {
    const float* src = (bx < 288) ? x : xavg;
    short* dhi = (bx < 288) ? Xh : Ah;
    const int bb = (bx < 288) ? bx : bx - 288;
    const int n0 = (bb % 36) * 64, c0 = ((bb / 36) & 3) * 64, b = bb / 144;
    __shared__ __align__(16) float T[64][68];
    {
      const int c = t >> 2, n4 = (t & 3) * 16;
      const float* sp = src + ((size_t)b * DIMC + c0 + c) * NPIX + n0 + n4;
#pragma unroll
      for (int i2 = 0; i2 < 4; ++i2)
        *(f32x4*)&T[c][n4 + i2 * 4] = *(const f32x4*)(sp + i2 * 4);
    }
    __syncthreads();
    {
      const int n = t >> 2, c4 = (t & 3) * 16;
      float v[16];
#pragma unroll
      for (int i = 0; i < 16; ++i) v[i] = T[c4 + i][n];
      uint32_t a[16];
#pragma unroll
      for (int i = 0; i < 16; ++i) a[i] = rnau(v[i]);
      union { s16x8 s; uint32_t u[4]; } H0, H1;
#pragma unroll
      for (int j = 0; j < 4; ++j) {
        H0.u[j] = pk2(a[2 * j], a[2 * j + 1]);
        H1.u[j] = pk2(a[8 + 2 * j], a[8 + 2 * j + 1]);
      }
      const size_t off = ((size_t)b * NPIX + n0 + n) * DIMC + c0 + c4;
      *(s16x8*)(dhi + off) = H0.s; *(s16x8*)(dhi + off + 8) = H1.s;
    }
  } else {
    const int idx = ((bx - 576) * 256 + t) * 8;
    const float* s;
    int off;
    if (idx < 65536)       { s = qw;  off = idx; }
    else if (idx < 196608) { s = kvw; off = idx - 65536; }
    else                   { s = pw_; off = idx - 196608; }
    f32x4 x0 = *(const f32x4*)(s + off);
    f32x4 x1 = *(const f32x4*)(s + off + 4);
    float v[8] = {x0[0], x0[1], x0[2], x0[3], x1[0], x1[1], x1[2], x1[3]};
    uint32_t a[8];
#pragma unroll
    for (int i = 0; i < 8; ++i) a[i] = rnau(v[i]);
    union { s16x8 s; uint32_t u[4]; } H;
#pragma unroll
    for (int j = 0; j < 4; ++j) H.u[j] = pk2(a[2 * j], a[2 * j + 1]);
    *(s16x8*)(Wth + idx) = H.s;
  }
}

// ---------------------------------------------------------------------------
// PROJ GEMM: single MFMA/tile (Wh*Zh). fp32 out + bias. UNCHANGED.
// ---------------------------------------------------------------------------
__global__ __launch_bounds__(128) void gemm_proj_hi(
    const short* __restrict__ Wh,
    const float* __restrict__ bias,
    const short* __restrict__ Zh,
    float* __restrict__ out) {
  __shared__ __align__(16) float Cl[32][68];
  const int n0 = blockIdx.x * 64;
  const int o0 = blockIdx.y * 32;
  const int b  = blockIdx.z;
  const int tid = threadIdx.x;
  const int wave = tid >> 6, lane = tid & 63;
  const int g = lane >> 4, q = lane & 15;

  const short* wph = Wh + ((o0 + wave * 16 + q) * DIMC + g * 8);
  const short* iph = Zh + ((size_t)(b * NPIX + n0 + q) * DIMC + g * 8);

  f32x4 acc[4] = {{0,0,0,0},{0,0,0,0},{0,0,0,0},{0,0,0,0}};
#pragma unroll
  for (int c0 = 0; c0 < DIMC; c0 += 32) {
    s16x8 ah = *(const s16x8*)(wph + c0);
#pragma unroll
    for (int st = 0; st < 4; ++st) {
      s16x8 bh_ = *(const s16x8*)(iph + (size_t)st * 16 * DIMC + c0);
      acc[st] = MFMA32(ah, bh_, acc[st]);
    }
  }
#pragma unroll
  for (int st = 0; st < 4; ++st)
#pragma unroll
    for (int r = 0; r < 4; ++r)
      Cl[wave * 16 + g * 4 + r][st * 16 + q] = acc[st][r];
  __syncthreads();

  const int o = tid >> 2, nc = (tid & 3) * 16;
  const float bv = bias[o0 + o];
  float* op = out + ((size_t)b * DIMC + o0 + o) * NPIX + n0 + nc;
#pragma unroll
  for (int i2 = 0; i2 < 4; ++i2) {
    f32x4 v = *(const f32x4*)&Cl[o][nc + i2 * 4];
    v[0] += bv; v[1] += bv; v[2] += bv; v[3] += bv;
    *(f32x4*)(op + i2 * 4) = v;
  }
}

// ---------------------------------------------------------------------------
// QKV GEMM: single MFMA/tile (Wh*Xh). UNCHANGED from R17.
// ---------------------------------------------------------------------------
__global__ __launch_bounds__(128) void gemm_qkv_hi(
    const short* __restrict__ Wth,
    const float* __restrict__ q_b, const float* __restrict__ kv_b,
    const short* __restrict__ Xh, const short* __restrict__ Ah,
    short* __restrict__ Qhi, short* __restrict__ Khi, short* __restrict__ Vhi,
    float qscale) {
  __shared__ __align__(16) float Cl[32][68];
  const int by = blockIdx.y;
  const bool isQ = (by < 8);
  const int o0 = isQ ? by * 32 : (by - 8) * 32;
  const short* Wh = isQ ? Wth : Wth + 65536;
  const float* bias = isQ ? q_b : kv_b;
  const short* Inh = isQ ? Xh : Ah;
  const float scale = isQ ? qscale : 1.0f;
  short* d1 = isQ ? Qhi : Khi;   // used when o0 < 256 (Q or K)
  const int n0 = blockIdx.x * 64;
  const int b  = blockIdx.z;

  const int tid = threadIdx.x;
  const int wave = tid >> 6, lane = tid & 63;
  const int g = lane >> 4, q = lane & 15;

  const short* wph = Wh + ((o0 + wave * 16 + q) * DIMC + g * 8);
  const short* iph = Inh + ((size_t)(b * NPIX + n0 + q) * DIMC + g * 8);

  f32x4 acc[4] = {{0,0,0,0},{0,0,0,0},{0,0,0,0},{0,0,0,0}};
#pragma unroll
  for (int c0 = 0; c0 < DIMC; c0 += 32) {
    s16x8 ah = *(const s16x8*)(wph + c0);
#pragma unroll
    for (int st = 0; st < 4; ++st) {
      s16x8 bh_ = *(const s16x8*)(iph + (size_t)st * 16 * DIMC + c0);
      acc[st] = MFMA32(ah, bh_, acc[st]);
    }
  }
#pragma unroll
  for (int st = 0; st < 4; ++st)
#pragma unroll
    for (int r = 0; r < 4; ++r)
      Cl[wave * 16 + g * 4 + r][st * 16 + q] = acc[st][r];
  __syncthreads();

  if (o0 < 256) {
    // Q or K: (C+bias)*scale, hi-only, layout [bh][n][32]
    const int n = tid >> 1, oq = tid & 1;
    const int h = o0 >> 5;
    const float* bp = bias + o0 + oq * 16;
    float v[16];
#pragma unroll
    for (int i = 0; i < 16; ++i) v[i] = (Cl[oq * 16 + i][n] + bp[i]) * scale;
    uint32_t a[16];
#pragma unroll
    for (int i = 0; i < 16; ++i) a[i] = rnau(v[i]);
    union { s16x8 s; uint32_t u[4]; } H0, H1;
#pragma unroll
    for (int j = 0; j < 4; ++j) {
      H0.u[j] = pk2(a[2 * j], a[2 * j + 1]);
      H1.u[j] = pk2(a[8 + 2 * j], a[8 + 2 * j + 1]);
    }
    const size_t off = ((size_t)((b * 8 + h) * NPIX + n0 + n)) * HD + oq * 16;
    *(s16x8*)(d1 + off) = H0.s; *(s16x8*)(d1 + off + 8) = H1.s;
  } else {
    // V hi-only: dst [bh][d][n]
    const int o = tid >> 2, nc = (tid & 3) * 16;
    const int h = (o0 - 256) >> 5;
    const float bv = bias[o0 + o];
    float v[16];
#pragma unroll
    for (int i2 = 0; i2 < 4; ++i2) {
      f32x4 t4 = *(const f32x4*)&Cl[o][nc + i2 * 4];
      v[i2 * 4 + 0] = t4[0] + bv; v[i2 * 4 + 1] = t4[1] + bv;
      v[i2 * 4 + 2] = t4[2] + bv; v[i2 * 4 + 3] = t4[3] + bv;
    }
    uint32_t a[16];
#pragma unroll
    for (int i = 0; i < 16; ++i) a[i] = rnau(v[i]);
    union { s16x8 s; uint32_t u[4]; } H0, H1;
#pragma unroll
    for (int j = 0; j < 4; ++j) {
      H0.u[j] = pk2(a[2 * j], a[2 * j + 1]);
      H1.u[j] = pk2(a[8 + 2 * j], a[8 + 2 * j + 1]);
    }
    const size_t off = ((size_t)((b * 8 + h) * HD + o)) * NPIX + n0 + nc;
    *(s16x8*)(Vhi + off) = H0.s; *(s16x8*)(Vhi + off + 8) = H1.s;
  }
}

// ---------------------------------------------------------------------------
// MFMA flash attention — R15 body; epilogue now stores part_o as BF16
// (halves the 28MB split-K intermediate write; merge unpacks).
// ---------------------------------------------------------------------------
__global__ __launch_bounds__(128) void attn_mfma(
    const short* __restrict__ Qhi,   // [bh][n][32]
    const short* __restrict__ Khi,   // [bh][n][32]
    const short* __restrict__ Vhi,   // [bh][32][N]
    short* __restrict__ part_o,      // [row][NSPLIT][32] bf16
    float* __restrict__ part_l) {    // [row][NSPLIT] f32
  const int sb = blockIdx.x;        // 0..575 = 16 bh * 36 qb
  const int bh = sb / 36;
  const int qb = sb % 36;           // 64-row block
  const int split = blockIdx.y;     // 0..NSPLIT-1
  const int tid = threadIdx.x;
  const int wave = tid >> 6, lane = tid & 63;
  const int g = lane >> 4, q = lane & 15;
  const int base = qb * 64 + wave * 32;

  __shared__ __align__(16) short Plds[2][2][16 * 40];
  short* pwA = &Plds[wave][0][0];
  short* pwB = &Plds[wave][1][0];

  const size_t qoff = ((size_t)bh * NPIX + base + q) * HD + g * 8;
  const s16x8 qhA = *(const s16x8*)(Qhi + qoff);
  const s16x8 qhB = *(const s16x8*)(Qhi + qoff + 16 * HD);

  const short* kp = Khi + ((size_t)bh * NPIX + split * KPS + q) * HD + g * 8;
  const short* vp = Vhi + ((size_t)bh * HD + q) * NPIX + split * KPS + g * 8;

  const f32x4 Z4 = {0.f, 0.f, 0.f, 0.f};
  f32x4 OA0 = Z4, OA1 = Z4, OB0 = Z4, OB1 = Z4;
  f32x4 LA = Z4, LB = Z4;
  s16x8 kb[3][2], vb[3][2], pfA, pfB, vp0, vp1;

  union { s16x8 s; uint32_t u[4]; } ONE;
  ONE.u[0] = 0x3F803F80u; ONE.u[1] = 0x3F803F80u;
  ONE.u[2] = 0x3F803F80u; ONE.u[3] = 0x3F803F80u;
  const s16x8 ones = ONE.s;

  kb[0][0] = *(const s16x8*)(kp);
  kb[0][1] = *(const s16x8*)(kp + 16 * HD);
  vb[0][0] = *(const s16x8*)(vp);
  vb[0][1] = *(const s16x8*)(vp + 16 * NPIX);
  kb[1][0] = *(const s16x8*)(kp + KT * HD);
  kb[1][1] = *(const s16x8*)(kp + KT * HD + 16 * HD);
  vb[1][0] = *(const s16x8*)(vp + KT);
  vb[1][1] = *(const s16x8*)(vp + KT + 16 * NPIX);

#pragma unroll
  for (int t = 0; t < NT; ++t) {
    const int cur = t % 3;
    if (t + 2 < NT) {
      const int nx2 = (t + 2) % 3;
      const short* kpn = kp + (t + 2) * (KT * HD);
      const short* vpn = vp + (t + 2) * KT;
      kb[nx2][0] = *(const s16x8*)(kpn);
      kb[nx2][1] = *(const s16x8*)(kpn + 16 * HD);
      vb[nx2][0] = *(const s16x8*)(vpn);
      vb[nx2][1] = *(const s16x8*)(vpn + 16 * NPIX);
    }
    f32x4 SA0 = MFMA32(kb[cur][0], qhA, Z4);
    f32x4 SA1 = MFMA32(kb[cur][1], qhA, Z4);
    f32x4 SB0 = MFMA32(kb[cur][0], qhB, Z4);
    f32x4 SB1 = MFMA32(kb[cur][1], qhB, Z4);
    if (t > 0) {
      OA0 = MFMA32(vp0, pfA, OA0);
      OA1 = MFMA32(vp1, pfA, OA1);
      OB0 = MFMA32(vp0, pfB, OB0);
      OB1 = MFMA32(vp1, pfB, OB1);
      LA  = MFMA32(ones, pfA, LA);
      LB  = MFMA32(ones, pfB, LB);
    }
    {
      f32x4 p0, p1;
#pragma unroll
      for (int r = 0; r < 4; ++r) { p0[r] = exp2f(SA0[r]); p1[r] = exp2f(SA1[r]); }
      uint2 w0, w1;
      w0.x = pk2(rnau(p0[0]), rnau(p0[1])); w0.y = pk2(rnau(p0[2]), rnau(p0[3]));
      w1.x = pk2(rnau(p1[0]), rnau(p1[1])); w1.y = pk2(rnau(p1[2]), rnau(p1[3]));
      *(uint2*)&pwA[q * 40 + g * 4] = w0;
      *(uint2*)&pwA[q * 40 + 16 + g * 4] = w1;
    }
    {
      f32x4 p0, p1;
#pragma unroll
      for (int r = 0; r < 4; ++r) { p0[r] = exp2f(SB0[r]); p1[r] = exp2f(SB1[r]); }
      uint2 w0, w1;
      w0.x = pk2(rnau(p0[0]), rnau(p0[1])); w0.y = pk2(rnau(p0[2]), rnau(p0[3]));
      w1.x = pk2(rnau(p1[0]), rnau(p1[1])); w1.y = pk2(rnau(p1[2]), rnau(p1[3]));
      *(uint2*)&pwB[q * 40 + g * 4] = w0;
      *(uint2*)&pwB[q * 40 + 16 + g * 4] = w1;
    }
    vp0 = vb[cur][0]; vp1 = vb[cur][1];
    pfA = *(const s16x8*)&pwA[q * 40 + g * 8];
    pfB = *(const s16x8*)&pwB[q * 40 + g * 8];
  }
  OA0 = MFMA32(vp0, pfA, OA0);
  OA1 = MFMA32(vp1, pfA, OA1);
  OB0 = MFMA32(vp0, pfB, OB0);
  OB1 = MFMA32(vp1, pfB, OB1);
  LA  = MFMA32(ones, pfA, LA);
  LB  = MFMA32(ones, pfB, LB);

  const int rowA = bh * NPIX + base + q;
  const int rowB = rowA + 16;
  short* poA = part_o + ((size_t)rowA * NSPLIT + split) * HD;
  short* poB = part_o + ((size_t)rowB * NSPLIT + split) * HD;
  uint2 wa0, wa1, wb0, wb1;
  wa0.x = pk2(rnau(OA0[0]), rnau(OA0[1])); wa0.y = pk2(rnau(OA0[2]), rnau(OA0[3]));
  wa1.x = pk2(rnau(OA1[0]), rnau(OA1[1])); wa1.y = pk2(rnau(OA1[2]), rnau(OA1[3]));
  wb0.x = pk2(rnau(OB0[0]), rnau(OB0[1])); wb0.y = pk2(rnau(OB0[2]), rnau(OB0[3]));
  wb1.x = pk2(rnau(OB1[0]), rnau(OB1[1])); wb1.y = pk2(rnau(OB1[2]), rnau(OB1[3]));
  *(uint2*)(poA + g * 4)      = wa0;   // d = g*4 + r
  *(uint2*)(poA + 16 + g * 4) = wa1;   // d = 16 + g*4 + r
  *(uint2*)(poB + g * 4)      = wb0;
  *(uint2*)(poB + 16 + g * 4) = wb1;
  if (g == 0) {
    part_l[(size_t)rowA * NSPLIT + split] = LA[0];
    part_l[(size_t)rowB * NSPLIT + split] = LB[0];
  }
}

// ---------------------------------------------------------------------------
// Merge splits (part_o now bf16), emit SCRAMBLED z HI-ONLY [b][p][256].
// ---------------------------------------------------------------------------
__global__ __launch_bounds__(288) void attn_merge(const short* __restrict__ part_o,
                                                  const float* __restrict__ part_l,
                                                  short* __restrict__ zh) {
  const int blk = blockIdx.x;          // 256 = 16 bh * 16
  const int bh = blk >> 4;
  const int n0 = (blk & 15) * 144;
  const int head = bh & 7, b = bh >> 3;
  const int t = threadIdx.x;
  __shared__ __align__(16) float T[144][36];
  {
    const int r = t >> 1, uh = (t & 1) * 4;   // r in 0..143
    const int idx = bh * NPIX + n0 + r;
    const float* pl = part_l + (size_t)idx * NSPLIT;
    float L = 0.f;
#pragma unroll
    for (int s = 0; s < NSPLIT; ++s) L += pl[s];
    const float inv = 1.f / L;
    const short* po = part_o + (size_t)idx * (NSPLIT * HD);
#pragma unroll
    for (int u = 0; u < 4; ++u) {
      f32x4 v = {0.f, 0.f, 0.f, 0.f};
#pragma unroll
      for (int s = 0; s < NSPLIT; ++s) {
        const uint2 w = *(const uint2*)(po + s * HD + (uh + u) * 4);
        v[0] += __uint_as_float(w.x << 16);
        v[1] += __uint_as_float(w.x & 0xffff0000u);
        v[2] += __uint_as_float(w.y << 16);
        v[3] += __uint_as_float(w.y & 0xffff0000u);
      }
      v[0] *= inv; v[1] *= inv; v[2] *= inv; v[3] *= inv;
      *(f32x4*)&T[r][(uh + u) * 4] = v;
    }
  }
  __syncthreads();
  {
    const int r9 = t / 32, dd = t & 31;    // r9 in 0..8
    const int p = r9 * 256 + head * HD + dd;
    const int c0 = n0 / 9;                  // 16 channels per chunk
    float v[16];
#pragma unroll
    for (int j = 0; j < 16; ++j) v[j] = T[9 * j + r9][dd];
    uint32_t a[16];
#pragma unroll
    for (int j = 0; j < 16; ++j) a[j] = rnau(v[j]);
    const size_t off = ((size_t)b * NPIX + p) * DIMC + c0;
#pragma unroll
    for (int c8 = 0; c8 < 2; ++c8) {
      union { s16x8 s; uint32_t u[4]; } H;
#pragma unroll
      for (int j = 0; j < 4; ++j)
        H.u[j] = pk2(a[c8 * 8 + 2 * j], a[c8 * 8 + 2 * j + 1]);
      *(s16x8*)(zh + off + c8 * 8) = H.s;
    }
  }
}

// ---------------------------------------------------------------------------
extern "C" void kernel_launch(void* const* d_in, const int* in_sizes, int n_in,
                              void* d_out, int out_size, void* d_ws, size_t ws_size,
                              hipStream_t stream) {
  const float* x      = (const float*)d_in[0];
  const float* q_w    = (const float*)d_in[1];
  const float* q_b    = (const float*)d_in[2];
  const float* kv_w   = (const float*)d_in[3];
  const float* kv_b   = (const float*)d_in[4];
  const float* proj_w = (const float*)d_in[5];
  const float* proj_b = (const float*)d_in[6];
  float* out = (float*)d_out;

  // Workspace (same offsets as R17; part_o now bf16, 14.2MB of its region).
  char* w = (char*)d_ws;
  float* xavg = (float*)w;                       // 4,718,592
  short* Xh   = (short*)(w + 4718592);
  short* Ah   = (short*)(w + 9437184);
  short* part_o = (short*)w;                     // 14,155,776 bf16 (aliases above)
  short* Wth  = (short*)(w + 28311552);          // 524,288 (hi only)
  short* Qhi  = (short*)(w + 29360128);          // 2,359,296
  short* Khi  = (short*)(w + 31719424);
  short* Vhi  = (short*)(w + 34078720);
  float* part_l = (float*)(w + 36438016);        // 884,736
  short* Zh   = (short*)(w + 37322752);          // 2,359,296

  const float qscale = 0.17677669529663689f * 1.4426950408889634f; // d^-0.5*log2(e)

  pool_kernel<<<BATCH * DIMC, 256, 0, stream>>>(x, xavg);
  conv_all<<<704, 256, 0, stream>>>(x, xavg, q_w, kv_w, proj_w, Xh, Ah, Wth);
  gemm_qkv_hi<<<dim3(36, 24, 2), 128, 0, stream>>>(Wth, q_b, kv_b,
                                                   Xh, Ah, Qhi, Khi, Vhi, qscale);
  attn_mfma<<<dim3(16 * 36, NSPLIT), 128, 0, stream>>>(Qhi, Khi, Vhi, part_o, part_l);
  attn_merge<<<256, 288, 0, stream>>>(part_o, part_l, Zh);
  gemm_proj_hi<<<dim3(36, 8, 2), 128, 0, stream>>>(Wth + 196608, proj_b, Zh, out);
}